// Round 1
// baseline (292.384 us; speedup 1.0000x reference)
//
#include <hip/hip_runtime.h>
#include <math.h>

#define B 4
#define T 2048
#define D 1024
#define S 64
#define NC 32      // chunks per batch
#define CH 64      // chunk length
#define NCOL 256   // padded projection columns (0..63 Wk, 64..127 Wv, 128..191 Wq, 192 Wg, rest 0)
#define TM 32      // token tile for proj / out kernels
#define KC 32      // K-chunk for proj

// ---------------------------------------------------------------- transpose W
__global__ __launch_bounds__(256) void k_transpose(const float* __restrict__ Wk,
                                                   const float* __restrict__ Wv,
                                                   const float* __restrict__ Wq,
                                                   const float* __restrict__ Wg,
                                                   float* __restrict__ Wt) {
  int idx = blockIdx.x * 256 + threadIdx.x;  // D*NCOL total
  if (idx >= D * NCOL) return;
  int kk = idx >> 8;        // /NCOL
  int c = idx & (NCOL - 1);
  float v = 0.f;
  if (c < 64)        v = Wk[c * D + kk];
  else if (c < 128)  v = Wv[(c - 64) * D + kk];
  else if (c < 192)  v = Wq[(c - 128) * D + kk];
  else if (c == 192) v = Wg[kk];
  Wt[idx] = v;
}

// ------------------------------------------- fused projection + RoPE + gates
__global__ __launch_bounds__(256) void k_proj(const float* __restrict__ x,
                                              const float* __restrict__ Wt,
                                              const float* __restrict__ cosT,
                                              const float* __restrict__ sinT,
                                              const float* __restrict__ bgp,
                                              float* __restrict__ qr,
                                              float* __restrict__ kr,
                                              float* __restrict__ av,
                                              float* __restrict__ logg) {
  __shared__ float xs[TM][36];        // [tok][kk], 36-pad keeps float4 alignment
  __shared__ float ws2[KC][NCOL];     // [kk][c], flat-staged (coalesced, conflict-free reads)
  int tid = threadIdx.x;
  int row0 = blockIdx.x * TM;
  int c4 = tid & 63, tg = tid >> 6;   // lane = output dim, wave = token group

  float acc[4][8];
#pragma unroll
  for (int g = 0; g < 4; ++g)
#pragma unroll
    for (int i = 0; i < 8; ++i) acc[g][i] = 0.f;

  for (int kc = 0; kc < D; kc += KC) {
    // stage x tile: 32 tok x 32 kk
    {
      int tok = tid >> 3, kk = (tid & 7) << 2;
      float4 v = *(const float4*)&x[(row0 + tok) * D + kc + kk];
      *(float4*)&xs[tok][kk] = v;
    }
    // stage W chunk flat (KC*NCOL floats, contiguous in Wt)
    {
      const float4* wsrc = (const float4*)&Wt[kc * NCOL];
      float4* wdst = (float4*)&ws2[0][0];
#pragma unroll
      for (int i = 0; i < (KC * NCOL / 4) / 256; ++i)
        wdst[tid + i * 256] = wsrc[tid + i * 256];
    }
    __syncthreads();
    for (int kk0 = 0; kk0 < KC; kk0 += 4) {
      float w[4][4];
#pragma unroll
      for (int u = 0; u < 4; ++u)
#pragma unroll
        for (int g = 0; g < 4; ++g) w[u][g] = ws2[kk0 + u][c4 + 64 * g];
#pragma unroll
      for (int i = 0; i < 8; ++i) {
        float4 xv = *(const float4*)&xs[tg * 8 + i][kk0];
#pragma unroll
        for (int g = 0; g < 4; ++g)
          acc[g][i] += xv.x * w[0][g] + xv.y * w[1][g] + xv.z * w[2][g] + xv.w * w[3][g];
      }
    }
    __syncthreads();
  }

  // epilogue: wave tg owns tokens tg*8 .. tg*8+7; lane c4 = dim
  float bg = bgp[0];
#pragma unroll
  for (int i = 0; i < 8; ++i) {
    int row = row0 + tg * 8 + i;
    int t = row & (T - 1);
    float k = acc[0][i], v = acc[1][i], q = acc[2][i];
    float z = __shfl(acc[3][i], 0, 64) + bg;   // column 192 lives in lane 0
    float cv = cosT[t * S + c4];
    float sv = sinT[t * S + c4];
    float kp = __shfl_xor(k, 32, 64);
    float qp = __shfl_xor(q, 32, 64);
    float krv = (c4 < 32) ? (k * cv - kp * sv) : (k * cv + kp * sv);
    float qrv = (c4 < 32) ? (q * cv - qp * sv) : (q * cv + qp * sv);
    float t2 = krv * krv;
#pragma unroll
    for (int off = 1; off < 64; off <<= 1) t2 += __shfl_xor(t2, off, 64);
    float alpha = 1.f / (1.f + expf(-z));
    float gate = alpha * t2 * 0.1f;
    float sp = (gate > 20.f) ? gate : log1pf(expf(gate));
    float g = expf(-sp);
    float lg = logf(g + 1e-8f);
    qr[row * S + c4] = qrv;
    kr[row * S + c4] = krv;
    av[row * S + c4] = alpha * v;
    if (c4 == 0) logg[row] = lg;
  }
}

// ---------------------------- per-chunk: local cumsum + chunk outer-product M
__global__ __launch_bounds__(256) void k_chunk(const float* __restrict__ kr,
                                               const float* __restrict__ av,
                                               const float* __restrict__ logg,
                                               float* __restrict__ lcum,
                                               float* __restrict__ csum,
                                               float* __restrict__ Mc) {
  int b = blockIdx.x >> 5, ch = blockIdx.x & 31;
  int rbase = b * T + ch * CH;
  __shared__ float lc[CH], wts[CH];
  __shared__ float krs[CH][65], avs[CH][65];
  int tid = threadIdx.x;

  if (tid < 64) {
    float v = logg[rbase + tid];
#pragma unroll
    for (int off = 1; off < 64; off <<= 1) {
      float n = __shfl_up(v, off, 64);
      if (tid >= off) v += n;
    }
    lc[tid] = v;
    lcum[rbase + tid] = v;
  }
  for (int i = tid; i < CH * S; i += 256) {
    int t = i >> 6, s = i & 63;
    krs[t][s] = kr[rbase * S + i];
    avs[t][s] = av[rbase * S + i];
  }
  __syncthreads();
  float tot = lc[63];
  if (tid < 64) wts[tid] = expf(tot - lc[tid]);   // exponent <= 0
  if (tid == 63) csum[b * NC + ch] = tot;
  __syncthreads();

  int k = tid & 63, vg = tid >> 6;
  float acc[16];
#pragma unroll
  for (int j = 0; j < 16; ++j) acc[j] = 0.f;
  for (int t = 0; t < CH; ++t) {
    float kw = krs[t][k] * wts[t];
#pragma unroll
    for (int j = 0; j < 16; ++j) acc[j] += kw * avs[t][vg * 16 + j];  // avs broadcast per wave
  }
  int obase = (b * NC + ch) * S * S;
#pragma unroll
  for (int j = 0; j < 16; ++j) Mc[obase + (vg * 16 + j) * S + k] = acc[j];
}

// ------------------------------- chunk-level scan: chunk-start states + new_state
__global__ __launch_bounds__(256) void k_scan(const float* __restrict__ state,
                                              const float* __restrict__ csum,
                                              const float* __restrict__ Mc,
                                              float* __restrict__ Sc,
                                              float* __restrict__ newstate) {
  int gid = blockIdx.x * 256 + threadIdx.x;  // B*S*S
  if (gid >= B * S * S) return;
  int b = gid >> 12, e = gid & 4095;
  float s = state[gid];
  for (int c = 0; c < NC; ++c) {
    int cb = (b * NC + c) * 4096;
    Sc[cb + e] = s;                       // state BEFORE chunk c
    s = s * expf(csum[b * NC + c]) + Mc[cb + e];
  }
  newstate[gid] = s;
}

// --------------------------------- intra-chunk attention + past-state retrieval
__global__ __launch_bounds__(256) void k_attn(const float* __restrict__ qr,
                                              const float* __restrict__ kr,
                                              const float* __restrict__ av,
                                              const float* __restrict__ lcum,
                                              const float* __restrict__ Sc,
                                              float* __restrict__ ret) {
  int b = blockIdx.x >> 5, ch = blockIdx.x & 31;
  int rbase = b * T + ch * CH;
  __shared__ float qs[CH][65], ks[CH][65], avs[CH][65], Ss[S][65], P[CH][65];
  __shared__ float lc[CH];
  int tid = threadIdx.x;
  if (tid < 64) lc[tid] = lcum[rbase + tid];
  {
    int scb = (b * NC + ch) * 4096;
    for (int i = tid; i < CH * S; i += 256) {
      int t = i >> 6, s = i & 63;
      qs[t][s] = qr[rbase * S + i];
      ks[t][s] = kr[rbase * S + i];
      avs[t][s] = av[rbase * S + i];
      Ss[t][s] = Sc[scb + i];
    }
  }
  __syncthreads();
  int lane = tid & 63, tg = tid >> 6;
  // P[t][s] = (q_t . k_s) * exp(shift_t - lc[s]) for s<t (chunk-local, strict causal)
  for (int i = 0; i < 16; ++i) {
    int t = tg * 16 + i;
    float dot = 0.f;
    for (int kk = 0; kk < S; ++kk) dot += qs[t][kk] * ks[lane][kk];
    float shift = (t == 0) ? 0.f : lc[t - 1];
    P[t][lane] = (lane < t) ? dot * expf(shift - lc[lane]) : 0.f;
  }
  __syncthreads();
  // ret[t][v] = sum_s P[t][s]*av[s][v]  +  (Sc @ q_t)[v]*exp(shift_t)
  for (int i = 0; i < 16; ++i) {
    int t = tg * 16 + i;
    float shift = (t == 0) ? 0.f : lc[t - 1];
    float r = 0.f;
    for (int kk = 0; kk < S; ++kk) r += Ss[lane][kk] * qs[t][kk];
    r *= expf(shift);
    for (int s = 0; s < CH; ++s) r += P[t][s] * avs[s][lane];
    ret[(rbase + t) * S + lane] = r;
  }
}

// ---------------------------------------------------------- output projection
__global__ __launch_bounds__(256) void k_out(const float* __restrict__ ret,
                                             const float* __restrict__ Wout,
                                             const float* __restrict__ bout,
                                             float* __restrict__ out) {
  __shared__ float rs[TM][68];   // 68-pad keeps float4 alignment
  int row0 = blockIdx.x * TM;
  int tid = threadIdx.x;
  for (int i = tid; i < TM * S; i += 256) rs[i >> 6][i & 63] = ret[row0 * S + i];
  __syncthreads();
  for (int j = 0; j < 4; ++j) {
    int d = j * 256 + tid;
    float4 w[16];
#pragma unroll
    for (int u = 0; u < 16; ++u) w[u] = *(const float4*)&Wout[d * S + u * 4];
    float bd = bout[d];
    for (int t = 0; t < TM; ++t) {
      float a = bd;
#pragma unroll
      for (int u = 0; u < 16; ++u) {
        float4 rv = *(const float4*)&rs[t][u * 4];  // broadcast
        a += rv.x * w[u].x + rv.y * w[u].y + rv.z * w[u].z + rv.w * w[u].w;
      }
      out[(row0 + t) * D + d] = a;
    }
  }
}

extern "C" void kernel_launch(void* const* d_in, const int* in_sizes, int n_in,
                              void* d_out, int out_size, void* d_ws, size_t ws_size,
                              hipStream_t stream) {
  (void)in_sizes; (void)n_in; (void)out_size; (void)ws_size;
  const float* x     = (const float*)d_in[0];
  const float* state = (const float*)d_in[1];
  const float* Wk    = (const float*)d_in[2];
  const float* Wv    = (const float*)d_in[3];
  const float* Wq    = (const float*)d_in[4];
  const float* Wout  = (const float*)d_in[5];
  const float* bout  = (const float*)d_in[6];
  const float* Wg    = (const float*)d_in[7];
  const float* bg    = (const float*)d_in[8];
  const float* cosT  = (const float*)d_in[9];
  const float* sinT  = (const float*)d_in[10];

  float* out = (float*)d_out;
  float* newstate = out + (size_t)B * T * D;

  float* ws   = (float*)d_ws;
  float* Wt   = ws;                       // D*NCOL
  float* qr   = Wt + D * NCOL;            // B*T*S
  float* kr   = qr + B * T * S;
  float* av   = kr + B * T * S;
  float* logg = av + B * T * S;           // B*T
  float* lcum = logg + B * T;             // B*T
  float* csum = lcum + B * T;             // B*NC
  float* Mc   = csum + B * NC;            // B*NC*S*S
  float* Sc   = Mc + B * NC * S * S;      // B*NC*S*S
  float* ret  = Sc + B * NC * S * S;      // B*T*S

  hipLaunchKernelGGL(k_transpose, dim3(D * NCOL / 256), dim3(256), 0, stream, Wk, Wv, Wq, Wg, Wt);
  hipLaunchKernelGGL(k_proj, dim3(B * T / TM), dim3(256), 0, stream, x, Wt, cosT, sinT, bg, qr, kr, av, logg);
  hipLaunchKernelGGL(k_chunk, dim3(B * NC), dim3(256), 0, stream, kr, av, logg, lcum, csum, Mc);
  hipLaunchKernelGGL(k_scan, dim3(B * S * S / 256), dim3(256), 0, stream, state, csum, Mc, Sc, newstate);
  hipLaunchKernelGGL(k_attn, dim3(B * NC), dim3(256), 0, stream, qr, kr, av, lcum, Sc, ret);
  hipLaunchKernelGGL(k_out, dim3(B * T / TM), dim3(256), 0, stream, ret, Wout, bout, out);
}

// Round 2
// 100.109 us; speedup vs baseline: 2.9206x; 2.9206x over previous
//
#include <hip/hip_runtime.h>
#include <math.h>

#define B 4
#define T 2048
#define D 1024
#define S 64
#define NC 32      // chunks per batch
#define CH 64      // chunk length

typedef float f32x4 __attribute__((ext_vector_type(4)));
typedef short bf16x8 __attribute__((ext_vector_type(8)));

__device__ inline ushort f2b(float f) {   // fp32 -> bf16 round-to-nearest-even
  unsigned u = __float_as_uint(f);
  u += 0x7fff + ((u >> 16) & 1);
  return (ushort)(u >> 16);
}

// ------------------------------------------------ weights -> bf16 (no transpose:
// Wk/Wv/Wq are [col][k] already = the MFMA B-operand layout; Wout is [n][k] too)
__global__ __launch_bounds__(256) void k_prep(const float* __restrict__ Wk,
                                              const float* __restrict__ Wv,
                                              const float* __restrict__ Wq,
                                              const float* __restrict__ Wg,
                                              const float* __restrict__ Wout,
                                              ushort* __restrict__ Wt,
                                              ushort* __restrict__ Wo) {
  int idx = blockIdx.x * 256 + threadIdx.x;
  if (idx < 256 * 1024) {
    int c = idx >> 10, kk = idx & 1023;
    float v = 0.f;
    if (c < 64)        v = Wk[c * D + kk];
    else if (c < 128)  v = Wv[(c - 64) * D + kk];
    else if (c < 192)  v = Wq[(c - 128) * D + kk];
    else if (c == 192) v = Wg[kk];
    Wt[idx] = f2b(v);
  } else {
    int j = idx - 256 * 1024;           // 1024*64 elems
    if (j < D * S) Wo[j] = f2b(Wout[j]);
  }
}

// ---------------------- fused bf16-MFMA projection + RoPE + gates (BM=32,BN=256)
__global__ __launch_bounds__(256) void k_proj(const float* __restrict__ x,
                                              const ushort* __restrict__ Wt,
                                              const float* __restrict__ cosT,
                                              const float* __restrict__ sinT,
                                              const float* __restrict__ bgp,
                                              float* __restrict__ qr,
                                              float* __restrict__ kr,
                                              float* __restrict__ av,
                                              float* __restrict__ logg) {
  __shared__ ushort lA[2][32 * 64];    // 4KB x2, rows = tokens, 64 bf16 k-cols
  __shared__ ushort lB[2][256 * 64];   // 32KB x2, rows = output cols
  __shared__ float s_alpha[32], s_knorm[32];
  int tid = threadIdx.x;
  int row0 = blockIdx.x * 32;
  int wv = tid >> 6, l = tid & 63, lr = l >> 4, lc = l & 15;

  f32x4 acc[2][4];
#pragma unroll
  for (int mi = 0; mi < 2; ++mi)
#pragma unroll
    for (int ni = 0; ni < 4; ++ni) acc[mi][ni] = (f32x4){0.f, 0.f, 0.f, 0.f};

  int arow = tid >> 3, ach = tid & 7;
  const int NT = D / 64;
  float af[8];
  uint4 bv[8];

  // ---- prologue: load+write tile 0
  {
    const float* ap = &x[(row0 + arow) * D + ach * 8];
    *(float4*)&af[0] = *(const float4*)ap;
    *(float4*)&af[4] = *(const float4*)(ap + 4);
#pragma unroll
    for (int it = 0; it < 8; ++it) {
      int g = tid + it * 256, brow = g >> 3, bch = g & 7;
      bv[it] = *(const uint4*)&Wt[brow * D + bch * 8];
    }
    union { ushort h[8]; uint4 v; } u;
#pragma unroll
    for (int j = 0; j < 8; ++j) u.h[j] = f2b(af[j]);
    *(uint4*)&lA[0][arow * 64 + ((ach ^ (arow & 7)) * 8)] = u.v;
#pragma unroll
    for (int it = 0; it < 8; ++it) {
      int g = tid + it * 256, brow = g >> 3, bch = g & 7;
      *(uint4*)&lB[0][brow * 64 + ((bch ^ (brow & 7)) * 8)] = bv[it];
    }
  }
  __syncthreads();

  for (int t = 0; t < NT; ++t) {
    int cur = t & 1;
    if (t + 1 < NT) {                       // issue next-tile loads early
      int kc = (t + 1) * 64;
      const float* ap = &x[(row0 + arow) * D + kc + ach * 8];
      *(float4*)&af[0] = *(const float4*)ap;
      *(float4*)&af[4] = *(const float4*)(ap + 4);
#pragma unroll
      for (int it = 0; it < 8; ++it) {
        int g = tid + it * 256, brow = g >> 3, bch = g & 7;
        bv[it] = *(const uint4*)&Wt[brow * D + kc + bch * 8];
      }
    }
    // ---- compute on buf cur
    bf16x8 afr[2][2], bfr[4][2];
#pragma unroll
    for (int mi = 0; mi < 2; ++mi)
#pragma unroll
      for (int ks = 0; ks < 2; ++ks)
        afr[mi][ks] = *(const bf16x8*)&lA[cur][(mi * 16 + lc) * 64 + (((ks * 4 + lr) ^ (lc & 7)) * 8)];
#pragma unroll
    for (int ni = 0; ni < 4; ++ni)
#pragma unroll
      for (int ks = 0; ks < 2; ++ks)
        bfr[ni][ks] = *(const bf16x8*)&lB[cur][(wv * 64 + ni * 16 + lc) * 64 + (((ks * 4 + lr) ^ (lc & 7)) * 8)];
#pragma unroll
    for (int ks = 0; ks < 2; ++ks)
#pragma unroll
      for (int mi = 0; mi < 2; ++mi)
#pragma unroll
        for (int ni = 0; ni < 4; ++ni)
          acc[mi][ni] = __builtin_amdgcn_mfma_f32_16x16x32_bf16(afr[mi][ks], bfr[ni][ks], acc[mi][ni], 0, 0, 0);
    __syncthreads();
    if (t + 1 < NT) {                       // write next tile into buf cur^1
      union { ushort h[8]; uint4 v; } u;
#pragma unroll
      for (int j = 0; j < 8; ++j) u.h[j] = f2b(af[j]);
      *(uint4*)&lA[cur ^ 1][arow * 64 + ((ach ^ (arow & 7)) * 8)] = u.v;
#pragma unroll
      for (int it = 0; it < 8; ++it) {
        int g = tid + it * 256, brow = g >> 3, bch = g & 7;
        *(uint4*)&lB[cur ^ 1][brow * 64 + ((bch ^ (brow & 7)) * 8)] = bv[it];
      }
    }
    __syncthreads();
  }

  // ---- epilogue. C/D map: row = mi*16 + lr*4 + r, col = wv*64 + ni*16 + lc.
  // wave0 = k-cols, wave1 = v, wave2 = q, wave3 col192 = gate logit.
  float bgv = bgp[0];
  if (wv == 0 || wv == 2) {
    float* dst = (wv == 0) ? kr : qr;
#pragma unroll
    for (int mi = 0; mi < 2; ++mi)
#pragma unroll
      for (int r = 0; r < 4; ++r) {
        int lrow = mi * 16 + lr * 4 + r;
        int grow = row0 + lrow;
        int tt = grow & (T - 1);
        float o[4];
#pragma unroll
        for (int ni = 0; ni < 4; ++ni) {
          int c = ni * 16 + lc;
          float cv = cosT[tt * S + c];
          float sv = sinT[tt * S + c];
          float a = acc[mi][ni][r];
          float p = acc[mi][ni ^ 2][r];   // RoPE partner c +/- 32 lives at ni^2
          o[ni] = (ni < 2) ? (a * cv - p * sv) : (a * cv + p * sv);
        }
        float nrm = o[0] * o[0] + o[1] * o[1] + o[2] * o[2] + o[3] * o[3];
#pragma unroll
        for (int off = 1; off < 16; off <<= 1) nrm += __shfl_xor(nrm, off, 64);
#pragma unroll
        for (int ni = 0; ni < 4; ++ni) dst[grow * S + ni * 16 + lc] = o[ni];
        if (wv == 0 && lc == 0) s_knorm[lrow] = nrm;
      }
  } else if (wv == 3) {
    if (lc == 0) {
#pragma unroll
      for (int mi = 0; mi < 2; ++mi)
#pragma unroll
        for (int r = 0; r < 4; ++r) {
          int lrow = mi * 16 + lr * 4 + r;
          float z = acc[mi][0][r] + bgv;
          s_alpha[lrow] = 1.f / (1.f + expf(-z));
        }
    }
  }
  __syncthreads();
  if (wv == 1) {
#pragma unroll
    for (int mi = 0; mi < 2; ++mi)
#pragma unroll
      for (int r = 0; r < 4; ++r) {
        int lrow = mi * 16 + lr * 4 + r;
        int grow = row0 + lrow;
        float al = s_alpha[lrow];
#pragma unroll
        for (int ni = 0; ni < 4; ++ni) av[grow * S + ni * 16 + lc] = al * acc[mi][ni][r];
      }
  } else if (wv == 3 && l < 32) {
    float al = s_alpha[l], kn = s_knorm[l];
    float gate = al * kn * 0.1f;
    float sp = (gate > 20.f) ? gate : log1pf(expf(gate));
    float g = expf(-sp);
    logg[row0 + l] = logf(g + 1e-8f);
  }
}

// ---------------------------- per-chunk: local cumsum + chunk outer-product M
__global__ __launch_bounds__(256) void k_chunk(const float* __restrict__ kr,
                                               const float* __restrict__ av,
                                               const float* __restrict__ logg,
                                               float* __restrict__ lcum,
                                               float* __restrict__ csum,
                                               float* __restrict__ Mc) {
  int b = blockIdx.x >> 5, ch = blockIdx.x & 31;
  int rbase = b * T + ch * CH;
  __shared__ float lc[CH], wts[CH];
  __shared__ float krs[CH][65], avs[CH][65];
  int tid = threadIdx.x;

  if (tid < 64) {
    float v = logg[rbase + tid];
#pragma unroll
    for (int off = 1; off < 64; off <<= 1) {
      float n = __shfl_up(v, off, 64);
      if (tid >= off) v += n;
    }
    lc[tid] = v;
    lcum[rbase + tid] = v;
  }
  for (int i = tid; i < CH * S; i += 256) {
    int t = i >> 6, s = i & 63;
    krs[t][s] = kr[rbase * S + i];
    avs[t][s] = av[rbase * S + i];
  }
  __syncthreads();
  float tot = lc[63];
  if (tid < 64) wts[tid] = expf(tot - lc[tid]);   // exponent <= 0
  if (tid == 63) csum[b * NC + ch] = tot;
  __syncthreads();

  int k = tid & 63, vg = tid >> 6;
  float acc[16];
#pragma unroll
  for (int j = 0; j < 16; ++j) acc[j] = 0.f;
  for (int t = 0; t < CH; ++t) {
    float kw = krs[t][k] * wts[t];
#pragma unroll
    for (int j = 0; j < 16; ++j) acc[j] += kw * avs[t][vg * 16 + j];
  }
  int obase = (b * NC + ch) * S * S;
#pragma unroll
  for (int j = 0; j < 16; ++j) Mc[obase + (vg * 16 + j) * S + k] = acc[j];
}

// ------------------------------- chunk-level scan: chunk-start states + new_state
__global__ __launch_bounds__(256) void k_scan(const float* __restrict__ state,
                                              const float* __restrict__ csum,
                                              const float* __restrict__ Mc,
                                              float* __restrict__ Sc,
                                              float* __restrict__ newstate) {
  int gid = blockIdx.x * 256 + threadIdx.x;  // B*S*S
  if (gid >= B * S * S) return;
  int b = gid >> 12, e = gid & 4095;
  float s = state[gid];
  for (int c = 0; c < NC; ++c) {
    int cb = (b * NC + c) * 4096;
    Sc[cb + e] = s;
    s = s * expf(csum[b * NC + c]) + Mc[cb + e];
  }
  newstate[gid] = s;
}

// --------------------------------- intra-chunk attention + past-state retrieval
__global__ __launch_bounds__(256) void k_attn(const float* __restrict__ qr,
                                              const float* __restrict__ kr,
                                              const float* __restrict__ av,
                                              const float* __restrict__ lcum,
                                              const float* __restrict__ Sc,
                                              ushort* __restrict__ retb) {
  int b = blockIdx.x >> 5, ch = blockIdx.x & 31;
  int rbase = b * T + ch * CH;
  __shared__ float qs[CH][65], ks[CH][65], avs[CH][65], Ss[S][65], P[CH][65];
  __shared__ float lc[CH];
  int tid = threadIdx.x;
  if (tid < 64) lc[tid] = lcum[rbase + tid];
  {
    int scb = (b * NC + ch) * 4096;
    for (int i = tid; i < CH * S; i += 256) {
      int t = i >> 6, s = i & 63;
      qs[t][s] = qr[rbase * S + i];
      ks[t][s] = kr[rbase * S + i];
      avs[t][s] = av[rbase * S + i];
      Ss[t][s] = Sc[scb + i];
    }
  }
  __syncthreads();
  int lane = tid & 63, tg = tid >> 6;
  for (int i = 0; i < 16; ++i) {
    int t = tg * 16 + i;
    float dot = 0.f;
    for (int kk = 0; kk < S; ++kk) dot += qs[t][kk] * ks[lane][kk];
    float shift = (t == 0) ? 0.f : lc[t - 1];
    P[t][lane] = (lane < t) ? dot * expf(shift - lc[lane]) : 0.f;
  }
  __syncthreads();
  for (int i = 0; i < 16; ++i) {
    int t = tg * 16 + i;
    float shift = (t == 0) ? 0.f : lc[t - 1];
    float r = 0.f;
    for (int kk = 0; kk < S; ++kk) r += Ss[lane][kk] * qs[t][kk];
    r *= expf(shift);
    for (int s = 0; s < CH; ++s) r += P[t][s] * avs[s][lane];
    retb[(rbase + t) * S + lane] = f2b(r);
  }
}

// ------------------------------ output projection: bf16 MFMA, M=8192 N=1024 K=64
__global__ __launch_bounds__(256) void k_out(const ushort* __restrict__ retb,
                                             const ushort* __restrict__ Wo,
                                             const float* __restrict__ bout,
                                             float* __restrict__ out) {
  __shared__ ushort lA[64 * 64];    // 8KB
  __shared__ ushort lB[128 * 64];   // 16KB
  int tid = threadIdx.x;
  int bm0 = (blockIdx.x & 127) * 64;
  int bn0 = (blockIdx.x >> 7) * 128;
#pragma unroll
  for (int it = 0; it < 2; ++it) {
    int g = tid + it * 256, row = g >> 3, ch = g & 7;
    uint4 v = *(const uint4*)&retb[(bm0 + row) * S + ch * 8];
    *(uint4*)&lA[row * 64 + ((ch ^ (row & 7)) * 8)] = v;
  }
#pragma unroll
  for (int it = 0; it < 4; ++it) {
    int g = tid + it * 256, row = g >> 3, ch = g & 7;
    uint4 v = *(const uint4*)&Wo[(bn0 + row) * S + ch * 8];
    *(uint4*)&lB[row * 64 + ((ch ^ (row & 7)) * 8)] = v;
  }
  __syncthreads();
  int wv = tid >> 6, l = tid & 63, lr = l >> 4, lc = l & 15;
  int wr = wv >> 1, wc = wv & 1;
  f32x4 acc[2][4];
#pragma unroll
  for (int mi = 0; mi < 2; ++mi)
#pragma unroll
    for (int ni = 0; ni < 4; ++ni) acc[mi][ni] = (f32x4){0.f, 0.f, 0.f, 0.f};
  bf16x8 afr[2][2], bfr[4][2];
#pragma unroll
  for (int mi = 0; mi < 2; ++mi)
#pragma unroll
    for (int ks = 0; ks < 2; ++ks)
      afr[mi][ks] = *(const bf16x8*)&lA[(wr * 32 + mi * 16 + lc) * 64 + (((ks * 4 + lr) ^ (lc & 7)) * 8)];
#pragma unroll
  for (int ni = 0; ni < 4; ++ni)
#pragma unroll
    for (int ks = 0; ks < 2; ++ks)
      bfr[ni][ks] = *(const bf16x8*)&lB[(wc * 64 + ni * 16 + lc) * 64 + (((ks * 4 + lr) ^ (lc & 7)) * 8)];
#pragma unroll
  for (int ks = 0; ks < 2; ++ks)
#pragma unroll
    for (int mi = 0; mi < 2; ++mi)
#pragma unroll
      for (int ni = 0; ni < 4; ++ni)
        acc[mi][ni] = __builtin_amdgcn_mfma_f32_16x16x32_bf16(afr[mi][ks], bfr[ni][ks], acc[mi][ni], 0, 0, 0);
  float bo[4];
#pragma unroll
  for (int ni = 0; ni < 4; ++ni) bo[ni] = bout[bn0 + wc * 64 + ni * 16 + lc];
#pragma unroll
  for (int mi = 0; mi < 2; ++mi)
#pragma unroll
    for (int r = 0; r < 4; ++r) {
      int grow = bm0 + wr * 32 + mi * 16 + lr * 4 + r;
#pragma unroll
      for (int ni = 0; ni < 4; ++ni)
        out[grow * D + bn0 + wc * 64 + ni * 16 + lc] = acc[mi][ni][r] + bo[ni];
    }
}

extern "C" void kernel_launch(void* const* d_in, const int* in_sizes, int n_in,
                              void* d_out, int out_size, void* d_ws, size_t ws_size,
                              hipStream_t stream) {
  (void)in_sizes; (void)n_in; (void)out_size; (void)ws_size;
  const float* x     = (const float*)d_in[0];
  const float* state = (const float*)d_in[1];
  const float* Wk    = (const float*)d_in[2];
  const float* Wv    = (const float*)d_in[3];
  const float* Wq    = (const float*)d_in[4];
  const float* Wout  = (const float*)d_in[5];
  const float* bout  = (const float*)d_in[6];
  const float* Wg    = (const float*)d_in[7];
  const float* bg    = (const float*)d_in[8];
  const float* cosT  = (const float*)d_in[9];
  const float* sinT  = (const float*)d_in[10];

  float* out = (float*)d_out;
  float* newstate = out + (size_t)B * T * D;

  ushort* Wt   = (ushort*)d_ws;                    // 256*1024 bf16
  ushort* Wo   = Wt + 256 * 1024;                  // 1024*64 bf16
  ushort* retb = Wo + 1024 * 64;                   // B*T*S bf16
  float* qr    = (float*)(retb + (size_t)B * T * S);
  float* kr    = qr + B * T * S;
  float* av    = kr + B * T * S;
  float* logg  = av + B * T * S;                   // B*T
  float* lcum  = logg + B * T;                     // B*T
  float* csum  = lcum + B * T;                     // B*NC
  float* Mc    = csum + B * NC;                    // B*NC*S*S
  float* Sc    = Mc + B * NC * S * S;              // B*NC*S*S

  hipLaunchKernelGGL(k_prep, dim3((256 * 1024 + D * S) / 256), dim3(256), 0, stream, Wk, Wv, Wq, Wg, Wout, Wt, Wo);
  hipLaunchKernelGGL(k_proj, dim3(B * T / 32), dim3(256), 0, stream, x, Wt, cosT, sinT, bg, qr, kr, av, logg);
  hipLaunchKernelGGL(k_chunk, dim3(B * NC), dim3(256), 0, stream, kr, av, logg, lcum, csum, Mc);
  hipLaunchKernelGGL(k_scan, dim3(B * S * S / 256), dim3(256), 0, stream, state, csum, Mc, Sc, newstate);
  hipLaunchKernelGGL(k_attn, dim3(B * NC), dim3(256), 0, stream, qr, kr, av, lcum, Sc, retb);
  hipLaunchKernelGGL(k_out, dim3((B * T / 64) * (D / 128)), dim3(256), 0, stream, retb, Wo, bout, out);
}

// Round 3
// 59.702 us; speedup vs baseline: 4.8974x; 1.6768x over previous
//
#include <hip/hip_runtime.h>
#include <math.h>

#define B 4
#define T 2048
#define D 1024
#define S 64
#define NC 32      // chunks per batch
#define CH 64      // chunk length

typedef float f32x4 __attribute__((ext_vector_type(4)));
typedef short bf16x8 __attribute__((ext_vector_type(8)));

__device__ inline ushort f2b(float f) {   // fp32 -> bf16 RNE
  unsigned u = __float_as_uint(f);
  u += 0x7fff + ((u >> 16) & 1);
  return (ushort)(u >> 16);
}
__device__ inline float b2f(ushort h) { return __uint_as_float(((unsigned)h) << 16); }

__device__ inline void gll16(const ushort* g, ushort* l) {
  __builtin_amdgcn_global_load_lds((const __attribute__((address_space(1))) void*)g,
                                   (__attribute__((address_space(3))) void*)l, 16, 0, 0);
}

// ---------------- weights -> bf16. Column order: k 0-63 | q 64-127 | v 128-191 | gate 192
__global__ __launch_bounds__(256) void k_prep(const float* __restrict__ Wk,
                                              const float* __restrict__ Wv,
                                              const float* __restrict__ Wq,
                                              const float* __restrict__ Wg,
                                              const float* __restrict__ Wout,
                                              ushort* __restrict__ Wt,
                                              ushort* __restrict__ Wo) {
  int idx = blockIdx.x * 256 + threadIdx.x;
  if (idx < 256 * 1024) {
    int c = idx >> 10, kk = idx & 1023;
    float v = 0.f;
    if (c < 64)        v = Wk[c * D + kk];
    else if (c < 128)  v = Wq[(c - 64) * D + kk];
    else if (c < 192)  v = Wv[(c - 128) * D + kk];
    else if (c == 192) v = Wg[kk];
    Wt[idx] = f2b(v);
  } else {
    int j = idx - 256 * 1024;
    if (j < D * S) Wo[j] = f2b(Wout[j]);
  }
}

// ---------------- bf16-MFMA projection, BM=32 BN=128, grid 512 (2 blocks/CU)
// cb=0 block: k+q cols (RoPE fused); cb=1 block: v+gate (av fused).
__global__ __launch_bounds__(256) void k_proj(const float* __restrict__ x,
                                              const ushort* __restrict__ Wt,
                                              const float* __restrict__ cosT,
                                              const float* __restrict__ sinT,
                                              const float* __restrict__ bgp,
                                              ushort* __restrict__ qrb,
                                              ushort* __restrict__ krb,
                                              ushort* __restrict__ avb,
                                              float* __restrict__ knw,
                                              float* __restrict__ alw) {
  __shared__ ushort lA[2][32 * 64];    // 4KB x2
  __shared__ ushort lB[2][128 * 64];   // 16KB x2
  __shared__ float s_red[2][32];
  int tid = threadIdx.x;
  int mt = blockIdx.x >> 1, cb = blockIdx.x & 1;
  int row0 = mt * 32, col0 = cb * 128;
  int wv = tid >> 6, l = tid & 63, lr = l >> 4, lc = l & 15;
  int arow = tid >> 3, ac8 = tid & 7;
  int gr_l = l >> 3, gc8 = l & 7;
  const float* xrow = &x[(size_t)(row0 + arow) * D + ((ac8 ^ (arow & 7)) << 3)];
  int f0 = ((wv >> 1) << 2) | (wv & 1);   // wave's first n-frag; pair is f0+2

  f32x4 acc[2][2];
#pragma unroll
  for (int mi = 0; mi < 2; ++mi)
#pragma unroll
    for (int ni = 0; ni < 2; ++ni) acc[mi][ni] = (f32x4){0.f, 0.f, 0.f, 0.f};

  float af[8];
  // prologue: tile 0 -> buf 0
  {
    *(float4*)&af[0] = *(const float4*)&xrow[0];
    *(float4*)&af[4] = *(const float4*)&xrow[4];
#pragma unroll
    for (int j = 0; j < 4; ++j) {
      int rloc = wv * 32 + j * 8 + gr_l;
      gll16(&Wt[(size_t)(col0 + rloc) * D + ((gc8 ^ (rloc & 7)) << 3)],
            (ushort*)&lB[0][(wv * 32 + j * 8) * 64]);
    }
    union { ushort h[8]; uint4 v; } u;
#pragma unroll
    for (int j = 0; j < 8; ++j) u.h[j] = f2b(af[j]);
    *(uint4*)&lA[0][arow * 64 + (ac8 << 3)] = u.v;
  }
  __syncthreads();

  const int NT = D / 64;
  for (int t = 0; t < NT; ++t) {
    int p = t & 1;
    if (t + 1 < NT) {
      int kc = (t + 1) * 64;
      *(float4*)&af[0] = *(const float4*)&xrow[kc];
      *(float4*)&af[4] = *(const float4*)&xrow[kc + 4];
#pragma unroll
      for (int j = 0; j < 4; ++j) {
        int rloc = wv * 32 + j * 8 + gr_l;
        gll16(&Wt[(size_t)(col0 + rloc) * D + kc + ((gc8 ^ (rloc & 7)) << 3)],
              (ushort*)&lB[p ^ 1][(wv * 32 + j * 8) * 64]);
      }
    }
    bf16x8 afr[2][2], bfr[2][2];
#pragma unroll
    for (int mi = 0; mi < 2; ++mi)
#pragma unroll
      for (int ks = 0; ks < 2; ++ks)
        afr[mi][ks] = *(const bf16x8*)&lA[p][(mi * 16 + lc) * 64 + (((ks * 4 + lr) ^ (lc & 7)) << 3)];
#pragma unroll
    for (int ni = 0; ni < 2; ++ni)
#pragma unroll
      for (int ks = 0; ks < 2; ++ks)
        bfr[ni][ks] = *(const bf16x8*)&lB[p][((f0 + 2 * ni) * 16 + lc) * 64 + (((ks * 4 + lr) ^ (lc & 7)) << 3)];
#pragma unroll
    for (int ks = 0; ks < 2; ++ks)
#pragma unroll
      for (int mi = 0; mi < 2; ++mi)
#pragma unroll
        for (int ni = 0; ni < 2; ++ni)
          acc[mi][ni] = __builtin_amdgcn_mfma_f32_16x16x32_bf16(afr[mi][ks], bfr[ni][ks], acc[mi][ni], 0, 0, 0);
    if (t + 1 < NT) {
      union { ushort h[8]; uint4 v; } u;
#pragma unroll
      for (int j = 0; j < 8; ++j) u.h[j] = f2b(af[j]);
      *(uint4*)&lA[p ^ 1][arow * 64 + (ac8 << 3)] = u.v;
    }
    __syncthreads();
  }

  // epilogue. C/D map: row = mi*16+lr*4+r, col(frag f) = f*16+lc.
  float bgv = bgp[0];
  int c0 = (wv & 1) * 16 + lc;   // col within the 64-wide group; partner c0+32
  if (cb == 0) {
    ushort* dst = (wv < 2) ? krb : qrb;
#pragma unroll
    for (int mi = 0; mi < 2; ++mi)
#pragma unroll
      for (int r = 0; r < 4; ++r) {
        int lrow = mi * 16 + lr * 4 + r;
        int grow = row0 + lrow;
        int tt = grow & (T - 1);
        float a0 = acc[mi][0][r], a1 = acc[mi][1][r];
        float cv0 = cosT[tt * S + c0], sv0 = sinT[tt * S + c0];
        float cv1 = cosT[tt * S + c0 + 32], sv1 = sinT[tt * S + c0 + 32];
        float o0 = a0 * cv0 - a1 * sv0;
        float o1 = a1 * cv1 + a0 * sv1;
        dst[(size_t)grow * S + c0] = f2b(o0);
        dst[(size_t)grow * S + c0 + 32] = f2b(o1);
        if (wv < 2) {
          float nrm = o0 * o0 + o1 * o1;
#pragma unroll
          for (int off = 1; off < 16; off <<= 1) nrm += __shfl_xor(nrm, off, 64);
          if (lc == 0) s_red[wv][lrow] = nrm;
        }
      }
    __syncthreads();
    if (tid < 32) knw[row0 + tid] = s_red[0][tid] + s_red[1][tid];
  } else {
    if (wv == 2 && lc == 0) {    // gate = local col 64 = frag 4, lc==0
#pragma unroll
      for (int mi = 0; mi < 2; ++mi)
#pragma unroll
        for (int r = 0; r < 4; ++r) {
          int lrow = mi * 16 + lr * 4 + r;
          s_red[0][lrow] = 1.f / (1.f + __expf(-(acc[mi][0][r] + bgv)));
        }
    }
    __syncthreads();
    if (wv < 2) {
#pragma unroll
      for (int mi = 0; mi < 2; ++mi)
#pragma unroll
        for (int r = 0; r < 4; ++r) {
          int lrow = mi * 16 + lr * 4 + r, grow = row0 + lrow;
          float al = s_red[0][lrow];
          avb[(size_t)grow * S + c0] = f2b(al * acc[mi][0][r]);
          avb[(size_t)grow * S + c0 + 32] = f2b(al * acc[mi][1][r]);
        }
    }
    if (tid < 32) alw[row0 + tid] = s_red[0][tid];
  }
}

// ---------------- per-chunk: gate+cumsum + outer-product Mc + avT; 2 blocks/chunk
__global__ __launch_bounds__(256) void k_chunk(const ushort* __restrict__ krb,
                                               const ushort* __restrict__ avb,
                                               const float* __restrict__ knw,
                                               const float* __restrict__ alw,
                                               float* __restrict__ lcum,
                                               float* __restrict__ csum,
                                               float* __restrict__ Mc,
                                               ushort* __restrict__ avT) {
  int cid = blockIdx.x >> 1, half = blockIdx.x & 1;
  int b = cid >> 5, ch = cid & 31;
  int rbase = b * T + ch * CH;
  __shared__ float lc[CH], wts[CH];
  __shared__ float krs[CH][65], avs[CH][65];
  int tid = threadIdx.x;

  if (tid < 64) {
    float al = alw[rbase + tid], kn = knw[rbase + tid];
    float gate = al * kn * 0.1f;
    float sp = (gate > 20.f) ? gate : log1pf(expf(gate));
    float g = expf(-sp);
    float v = logf(g + 1e-8f);
#pragma unroll
    for (int off = 1; off < 64; off <<= 1) {
      float n = __shfl_up(v, off, 64);
      if (tid >= off) v += n;
    }
    lc[tid] = v;
    if (half == 0) lcum[rbase + tid] = v;
  }
  for (int i = tid; i < CH * S / 8; i += 256) {
    int t = i >> 3, c8 = i & 7;
    uint4 kv = *(const uint4*)&krb[(size_t)(rbase + t) * S + c8 * 8];
    uint4 a4 = *(const uint4*)&avb[(size_t)(rbase + t) * S + c8 * 8];
    const ushort* kh = (const ushort*)&kv;
    const ushort* ah = (const ushort*)&a4;
#pragma unroll
    for (int j = 0; j < 8; ++j) {
      krs[t][c8 * 8 + j] = b2f(kh[j]);
      avs[t][c8 * 8 + j] = b2f(ah[j]);
    }
  }
  __syncthreads();
  float tot = lc[63];
  if (tid < 64) wts[tid] = __expf(tot - lc[tid]);   // exponent <= 0
  if (tid == 63 && half == 0) csum[b * NC + ch] = tot;
  __syncthreads();
  for (int i = tid; i < 2048; i += 256) {           // this half's v-range transpose
    int v = half * 32 + (i >> 6), t = i & 63;
    avT[(size_t)(b * NC + ch) * 4096 + v * 64 + t] = f2b(avs[t][v]);
  }
  int k = tid & 63, vg = tid >> 6;
  int v0 = half * 32 + vg * 8;
  float acc[8];
#pragma unroll
  for (int j = 0; j < 8; ++j) acc[j] = 0.f;
  for (int t = 0; t < CH; ++t) {
    float kw = krs[t][k] * wts[t];
#pragma unroll
    for (int j = 0; j < 8; ++j) acc[j] += kw * avs[t][v0 + j];
  }
  size_t ob = (size_t)(b * NC + ch) * 4096;
#pragma unroll
  for (int j = 0; j < 8; ++j) Mc[ob + (v0 + j) * 64 + k] = acc[j];
}

// ---------------- chunk-level scan
__global__ __launch_bounds__(256) void k_scan(const float* __restrict__ state,
                                              const float* __restrict__ csum,
                                              const float* __restrict__ Mc,
                                              ushort* __restrict__ Scb,
                                              float* __restrict__ newstate) {
  int gid = blockIdx.x * 256 + threadIdx.x;
  if (gid >= B * S * S) return;
  int b = gid >> 12, e = gid & 4095;
  float s = state[gid];
  for (int c = 0; c < NC; ++c) {
    size_t cb2 = (size_t)(b * NC + c) * 4096;
    Scb[cb2 + e] = f2b(s);
    s = s * __expf(csum[b * NC + c]) + Mc[cb2 + e];
  }
  newstate[gid] = s;
}

// ---------------- intra-chunk attention: 3 MFMA GEMMs per chunk
__global__ __launch_bounds__(256) void k_attn(const ushort* __restrict__ qrb,
                                              const ushort* __restrict__ krb,
                                              const ushort* __restrict__ avT,
                                              const ushort* __restrict__ Scb,
                                              const float* __restrict__ lcum,
                                              ushort* __restrict__ retb) {
  int b = blockIdx.x >> 5, ch = blockIdx.x & 31;
  int rbase = b * T + ch * CH;
  size_t cb2 = (size_t)(b * NC + ch) * 4096;
  __shared__ ushort qs[64 * 64], ks_[64 * 64], vs[64 * 64], ss[64 * 64], ps[64 * 64];
  __shared__ float lcv[CH];
  int tid = threadIdx.x;
  if (tid < 64) lcv[tid] = lcum[rbase + tid];
  for (int i = tid; i < 512; i += 256) {
    int row = i >> 3, c8 = i & 7;
    int sc = (c8 ^ (row & 7)) << 3;
    *(uint4*)&qs[row * 64 + c8 * 8]  = *(const uint4*)&qrb[(size_t)(rbase + row) * S + sc];
    *(uint4*)&ks_[row * 64 + c8 * 8] = *(const uint4*)&krb[(size_t)(rbase + row) * S + sc];
    *(uint4*)&vs[row * 64 + c8 * 8]  = *(const uint4*)&avT[cb2 + row * 64 + sc];
    *(uint4*)&ss[row * 64 + c8 * 8]  = *(const uint4*)&Scb[cb2 + row * 64 + sc];
  }
  __syncthreads();
  int wv = tid >> 6, l = tid & 63, lr = l >> 4, lc = l & 15;
  int tq = (wv >> 1) * 32, oq = (wv & 1) * 32;
  f32x4 a1[2][2], a2[2][2];
#pragma unroll
  for (int mi = 0; mi < 2; ++mi)
#pragma unroll
    for (int ni = 0; ni < 2; ++ni) { a1[mi][ni] = (f32x4){0,0,0,0}; a2[mi][ni] = (f32x4){0,0,0,0}; }

  bf16x8 qa[2][2];
#pragma unroll
  for (int mi = 0; mi < 2; ++mi)
#pragma unroll
    for (int ks = 0; ks < 2; ++ks)
      qa[mi][ks] = *(const bf16x8*)&qs[(tq + mi * 16 + lc) * 64 + (((ks * 4 + lr) ^ (lc & 7)) << 3)];
#pragma unroll
  for (int ni = 0; ni < 2; ++ni)
#pragma unroll
    for (int ks = 0; ks < 2; ++ks) {
      bf16x8 kf = *(const bf16x8*)&ks_[(oq + ni * 16 + lc) * 64 + (((ks * 4 + lr) ^ (lc & 7)) << 3)];
      bf16x8 sf = *(const bf16x8*)&ss[(oq + ni * 16 + lc) * 64 + (((ks * 4 + lr) ^ (lc & 7)) << 3)];
#pragma unroll
      for (int mi = 0; mi < 2; ++mi) {
        a1[mi][ni] = __builtin_amdgcn_mfma_f32_16x16x32_bf16(qa[mi][ks], kf, a1[mi][ni], 0, 0, 0);
        a2[mi][ni] = __builtin_amdgcn_mfma_f32_16x16x32_bf16(qa[mi][ks], sf, a2[mi][ni], 0, 0, 0);
      }
    }
  // P = mask(dot)*exp(sh_t - lc_s) -> ps (swizzled); a2 *= exp(sh_t)
#pragma unroll
  for (int mi = 0; mi < 2; ++mi)
#pragma unroll
    for (int r = 0; r < 4; ++r) {
      int trow = tq + mi * 16 + lr * 4 + r;
      float sh = trow ? lcv[trow - 1] : 0.f;
      float esh = __expf(sh);
#pragma unroll
      for (int ni = 0; ni < 2; ++ni) {
        int scol = oq + ni * 16 + lc;
        float pv = (scol < trow) ? a1[mi][ni][r] * __expf(sh - lcv[scol]) : 0.f;
        ps[trow * 64 + (((scol >> 3) ^ (trow & 7)) << 3) + (scol & 7)] = f2b(pv);
        a2[mi][ni][r] *= esh;
      }
    }
  __syncthreads();
  // GEMM3: ret += P @ avT
  bf16x8 pa[2][2];
#pragma unroll
  for (int mi = 0; mi < 2; ++mi)
#pragma unroll
    for (int ks = 0; ks < 2; ++ks)
      pa[mi][ks] = *(const bf16x8*)&ps[(tq + mi * 16 + lc) * 64 + (((ks * 4 + lr) ^ (lc & 7)) << 3)];
#pragma unroll
  for (int ni = 0; ni < 2; ++ni)
#pragma unroll
    for (int ks = 0; ks < 2; ++ks) {
      bf16x8 vf = *(const bf16x8*)&vs[(oq + ni * 16 + lc) * 64 + (((ks * 4 + lr) ^ (lc & 7)) << 3)];
#pragma unroll
      for (int mi = 0; mi < 2; ++mi)
        a2[mi][ni] = __builtin_amdgcn_mfma_f32_16x16x32_bf16(pa[mi][ks], vf, a2[mi][ni], 0, 0, 0);
    }
#pragma unroll
  for (int mi = 0; mi < 2; ++mi)
#pragma unroll
    for (int r = 0; r < 4; ++r) {
      int trow = tq + mi * 16 + lr * 4 + r;
#pragma unroll
      for (int ni = 0; ni < 2; ++ni)
        retb[(size_t)(rbase + trow) * S + oq + ni * 16 + lc] = f2b(a2[mi][ni][r]);
    }
}

// ---------------- output projection: bf16 MFMA, M=8192 N=1024 K=64
__global__ __launch_bounds__(256) void k_out(const ushort* __restrict__ retb,
                                             const ushort* __restrict__ Wo,
                                             const float* __restrict__ bout,
                                             float* __restrict__ out) {
  __shared__ ushort lA[64 * 64];
  __shared__ ushort lB[128 * 64];
  int tid = threadIdx.x;
  int bm0 = (blockIdx.x & 127) * 64;
  int bn0 = (blockIdx.x >> 7) * 128;
#pragma unroll
  for (int it = 0; it < 2; ++it) {
    int g = tid + it * 256, row = g >> 3, ch = g & 7;
    uint4 v = *(const uint4*)&retb[(size_t)(bm0 + row) * S + ch * 8];
    *(uint4*)&lA[row * 64 + ((ch ^ (row & 7)) * 8)] = v;
  }
#pragma unroll
  for (int it = 0; it < 4; ++it) {
    int g = tid + it * 256, row = g >> 3, ch = g & 7;
    uint4 v = *(const uint4*)&Wo[(size_t)(bn0 + row) * S + ch * 8];
    *(uint4*)&lB[row * 64 + ((ch ^ (row & 7)) * 8)] = v;
  }
  __syncthreads();
  int wv = tid >> 6, l = tid & 63, lr = l >> 4, lc = l & 15;
  int wr = wv >> 1, wc = wv & 1;
  f32x4 acc[2][4];
#pragma unroll
  for (int mi = 0; mi < 2; ++mi)
#pragma unroll
    for (int ni = 0; ni < 4; ++ni) acc[mi][ni] = (f32x4){0.f, 0.f, 0.f, 0.f};
  bf16x8 afr[2][2], bfr[4][2];
#pragma unroll
  for (int mi = 0; mi < 2; ++mi)
#pragma unroll
    for (int ks = 0; ks < 2; ++ks)
      afr[mi][ks] = *(const bf16x8*)&lA[(wr * 32 + mi * 16 + lc) * 64 + (((ks * 4 + lr) ^ (lc & 7)) * 8)];
#pragma unroll
  for (int ni = 0; ni < 4; ++ni)
#pragma unroll
    for (int ks = 0; ks < 2; ++ks)
      bfr[ni][ks] = *(const bf16x8*)&lB[(wc * 64 + ni * 16 + lc) * 64 + (((ks * 4 + lr) ^ (lc & 7)) * 8)];
#pragma unroll
  for (int ks = 0; ks < 2; ++ks)
#pragma unroll
    for (int mi = 0; mi < 2; ++mi)
#pragma unroll
      for (int ni = 0; ni < 4; ++ni)
        acc[mi][ni] = __builtin_amdgcn_mfma_f32_16x16x32_bf16(afr[mi][ks], bfr[ni][ks], acc[mi][ni], 0, 0, 0);
  float bo[4];
#pragma unroll
  for (int ni = 0; ni < 4; ++ni) bo[ni] = bout[bn0 + wc * 64 + ni * 16 + lc];
#pragma unroll
  for (int mi = 0; mi < 2; ++mi)
#pragma unroll
    for (int r = 0; r < 4; ++r) {
      int grow = bm0 + wr * 32 + mi * 16 + lr * 4 + r;
#pragma unroll
      for (int ni = 0; ni < 4; ++ni)
        out[(size_t)grow * D + bn0 + wc * 64 + ni * 16 + lc] = acc[mi][ni][r] + bo[ni];
    }
}

extern "C" void kernel_launch(void* const* d_in, const int* in_sizes, int n_in,
                              void* d_out, int out_size, void* d_ws, size_t ws_size,
                              hipStream_t stream) {
  (void)in_sizes; (void)n_in; (void)out_size; (void)ws_size;
  const float* x     = (const float*)d_in[0];
  const float* state = (const float*)d_in[1];
  const float* Wk    = (const float*)d_in[2];
  const float* Wv    = (const float*)d_in[3];
  const float* Wq    = (const float*)d_in[4];
  const float* Wout  = (const float*)d_in[5];
  const float* bout  = (const float*)d_in[6];
  const float* Wg    = (const float*)d_in[7];
  const float* bg    = (const float*)d_in[8];
  const float* cosT  = (const float*)d_in[9];
  const float* sinT  = (const float*)d_in[10];

  float* out = (float*)d_out;
  float* newstate = out + (size_t)B * T * D;

  const int NTOK = B * T;            // 8192
  const int NE = B * T * S;          // 524288
  ushort* Wt   = (ushort*)d_ws;      // 262144
  ushort* Wo   = Wt + 262144;        // 65536
  ushort* qrb  = Wo + 65536;
  ushort* krb  = qrb + NE;
  ushort* avb  = krb + NE;
  ushort* avT  = avb + NE;
  ushort* Scb  = avT + NE;           // B*NC*4096 = NE
  ushort* retb = Scb + NE;
  float* knw   = (float*)(retb + NE);
  float* alw   = knw + NTOK;
  float* lcum  = alw + NTOK;
  float* csum  = lcum + NTOK;        // B*NC
  float* Mc    = csum + B * NC;      // NE floats

  hipLaunchKernelGGL(k_prep, dim3(1280), dim3(256), 0, stream, Wk, Wv, Wq, Wg, Wout, Wt, Wo);
  hipLaunchKernelGGL(k_proj, dim3(NTOK / 32 * 2), dim3(256), 0, stream, x, Wt, cosT, sinT, bg, qrb, krb, avb, knw, alw);
  hipLaunchKernelGGL(k_chunk, dim3(B * NC * 2), dim3(256), 0, stream, krb, avb, knw, alw, lcum, csum, Mc, avT);
  hipLaunchKernelGGL(k_scan, dim3(B * S * S / 256), dim3(256), 0, stream, state, csum, Mc, Scb, newstate);
  hipLaunchKernelGGL(k_attn, dim3(B * NC), dim3(256), 0, stream, qrb, krb, avT, Scb, lcum, retb);
  hipLaunchKernelGGL(k_out, dim3((NTOK / 64) * (D / 128)), dim3(256), 0, stream, retb, Wo, bout, out);
}

// Round 4
// 55.249 us; speedup vs baseline: 5.2921x; 1.0806x over previous
//
#include <hip/hip_runtime.h>
#include <math.h>

#define B 4
#define T 2048
#define D 1024
#define S 64
#define NC 32      // chunks per batch
#define CH 64      // chunk length

typedef float f32x4 __attribute__((ext_vector_type(4)));
typedef short bf16x8 __attribute__((ext_vector_type(8)));

__device__ inline ushort f2b(float f) {   // fp32 -> bf16 RNE
  unsigned u = __float_as_uint(f);
  u += 0x7fff + ((u >> 16) & 1);
  return (ushort)(u >> 16);
}
__device__ inline float b2f(ushort h) { return __uint_as_float(((unsigned)h) << 16); }

__device__ inline void gll16(const ushort* g, ushort* l) {
  __builtin_amdgcn_global_load_lds((const __attribute__((address_space(1))) void*)g,
                                   (__attribute__((address_space(3))) void*)l, 16, 0, 0);
}

// ---------------- weights -> bf16. Column order: k 0-63 | q 64-127 | v 128-191 | gate 192
__global__ __launch_bounds__(256) void k_prep(const float* __restrict__ Wk,
                                              const float* __restrict__ Wv,
                                              const float* __restrict__ Wq,
                                              const float* __restrict__ Wg,
                                              const float* __restrict__ Wout,
                                              ushort* __restrict__ Wt,
                                              ushort* __restrict__ Wo) {
  int idx = blockIdx.x * 256 + threadIdx.x;
  if (idx < 256 * 1024) {
    int c = idx >> 10, kk = idx & 1023;
    float v = 0.f;
    if (c < 64)        v = Wk[c * D + kk];
    else if (c < 128)  v = Wq[(c - 64) * D + kk];
    else if (c < 192)  v = Wv[(c - 128) * D + kk];
    else if (c == 192) v = Wg[kk];
    Wt[idx] = f2b(v);
  } else {
    int j = idx - 256 * 1024;
    if (j < D * S) Wo[j] = f2b(Wout[j]);
  }
}

// ---------------- bf16-MFMA projection, BM=32 BN=128, grid 512 (2 blocks/CU)
// cb=0 block: k+q cols (RoPE fused); cb=1 block: v+gate (av fused).
__global__ __launch_bounds__(256) void k_proj(const float* __restrict__ x,
                                              const ushort* __restrict__ Wt,
                                              const float* __restrict__ cosT,
                                              const float* __restrict__ sinT,
                                              const float* __restrict__ bgp,
                                              ushort* __restrict__ qrb,
                                              ushort* __restrict__ krb,
                                              ushort* __restrict__ avb,
                                              float* __restrict__ knw,
                                              float* __restrict__ alw) {
  __shared__ ushort lA[2][32 * 64];    // 4KB x2
  __shared__ ushort lB[2][128 * 64];   // 16KB x2
  __shared__ float s_red[2][32];
  int tid = threadIdx.x;
  int mt = blockIdx.x >> 1, cb = blockIdx.x & 1;
  int row0 = mt * 32, col0 = cb * 128;
  int wv = tid >> 6, l = tid & 63, lr = l >> 4, lc = l & 15;
  int arow = tid >> 3, ac8 = tid & 7;
  int gr_l = l >> 3, gc8 = l & 7;
  const float* xrow = &x[(size_t)(row0 + arow) * D + ((ac8 ^ (arow & 7)) << 3)];
  int f0 = ((wv >> 1) << 2) | (wv & 1);   // wave's first n-frag; pair is f0+2

  f32x4 acc[2][2];
#pragma unroll
  for (int mi = 0; mi < 2; ++mi)
#pragma unroll
    for (int ni = 0; ni < 2; ++ni) acc[mi][ni] = (f32x4){0.f, 0.f, 0.f, 0.f};

  float af[8];
  // prologue: tile 0 -> buf 0
  {
    *(float4*)&af[0] = *(const float4*)&xrow[0];
    *(float4*)&af[4] = *(const float4*)&xrow[4];
#pragma unroll
    for (int j = 0; j < 4; ++j) {
      int rloc = wv * 32 + j * 8 + gr_l;
      gll16(&Wt[(size_t)(col0 + rloc) * D + ((gc8 ^ (rloc & 7)) << 3)],
            (ushort*)&lB[0][(wv * 32 + j * 8) * 64]);
    }
    union { ushort h[8]; uint4 v; } u;
#pragma unroll
    for (int j = 0; j < 8; ++j) u.h[j] = f2b(af[j]);
    *(uint4*)&lA[0][arow * 64 + (ac8 << 3)] = u.v;
  }
  __syncthreads();

  const int NT = D / 64;
  for (int t = 0; t < NT; ++t) {
    int p = t & 1;
    if (t + 1 < NT) {
      int kc = (t + 1) * 64;
      *(float4*)&af[0] = *(const float4*)&xrow[kc];
      *(float4*)&af[4] = *(const float4*)&xrow[kc + 4];
#pragma unroll
      for (int j = 0; j < 4; ++j) {
        int rloc = wv * 32 + j * 8 + gr_l;
        gll16(&Wt[(size_t)(col0 + rloc) * D + kc + ((gc8 ^ (rloc & 7)) << 3)],
              (ushort*)&lB[p ^ 1][(wv * 32 + j * 8) * 64]);
      }
    }
    bf16x8 afr[2][2], bfr[2][2];
#pragma unroll
    for (int mi = 0; mi < 2; ++mi)
#pragma unroll
      for (int ks = 0; ks < 2; ++ks)
        afr[mi][ks] = *(const bf16x8*)&lA[p][(mi * 16 + lc) * 64 + (((ks * 4 + lr) ^ (lc & 7)) << 3)];
#pragma unroll
    for (int ni = 0; ni < 2; ++ni)
#pragma unroll
      for (int ks = 0; ks < 2; ++ks)
        bfr[ni][ks] = *(const bf16x8*)&lB[p][((f0 + 2 * ni) * 16 + lc) * 64 + (((ks * 4 + lr) ^ (lc & 7)) << 3)];
#pragma unroll
    for (int ks = 0; ks < 2; ++ks)
#pragma unroll
      for (int mi = 0; mi < 2; ++mi)
#pragma unroll
        for (int ni = 0; ni < 2; ++ni)
          acc[mi][ni] = __builtin_amdgcn_mfma_f32_16x16x32_bf16(afr[mi][ks], bfr[ni][ks], acc[mi][ni], 0, 0, 0);
    if (t + 1 < NT) {
      union { ushort h[8]; uint4 v; } u;
#pragma unroll
      for (int j = 0; j < 8; ++j) u.h[j] = f2b(af[j]);
      *(uint4*)&lA[p ^ 1][arow * 64 + (ac8 << 3)] = u.v;
    }
    __syncthreads();
  }

  // epilogue. C/D map: row = mi*16+lr*4+r, col(frag f) = f*16+lc.
  float bgv = bgp[0];
  int c0 = (wv & 1) * 16 + lc;   // col within the 64-wide group; partner c0+32
  if (cb == 0) {
    ushort* dst = (wv < 2) ? krb : qrb;
#pragma unroll
    for (int mi = 0; mi < 2; ++mi)
#pragma unroll
      for (int r = 0; r < 4; ++r) {
        int lrow = mi * 16 + lr * 4 + r;
        int grow = row0 + lrow;
        int tt = grow & (T - 1);
        float a0 = acc[mi][0][r], a1 = acc[mi][1][r];
        float cv0 = cosT[tt * S + c0], sv0 = sinT[tt * S + c0];
        float cv1 = cosT[tt * S + c0 + 32], sv1 = sinT[tt * S + c0 + 32];
        float o0 = a0 * cv0 - a1 * sv0;
        float o1 = a1 * cv1 + a0 * sv1;
        dst[(size_t)grow * S + c0] = f2b(o0);
        dst[(size_t)grow * S + c0 + 32] = f2b(o1);
        if (wv < 2) {
          float nrm = o0 * o0 + o1 * o1;
#pragma unroll
          for (int off = 1; off < 16; off <<= 1) nrm += __shfl_xor(nrm, off, 64);
          if (lc == 0) s_red[wv][lrow] = nrm;
        }
      }
    __syncthreads();
    if (tid < 32) knw[row0 + tid] = s_red[0][tid] + s_red[1][tid];
  } else {
    if (wv == 2 && lc == 0) {    // gate = local col 64 = frag 4, lc==0
#pragma unroll
      for (int mi = 0; mi < 2; ++mi)
#pragma unroll
        for (int r = 0; r < 4; ++r) {
          int lrow = mi * 16 + lr * 4 + r;
          s_red[0][lrow] = 1.f / (1.f + __expf(-(acc[mi][0][r] + bgv)));
        }
    }
    __syncthreads();
    if (wv < 2) {
#pragma unroll
      for (int mi = 0; mi < 2; ++mi)
#pragma unroll
        for (int r = 0; r < 4; ++r) {
          int lrow = mi * 16 + lr * 4 + r, grow = row0 + lrow;
          float al = s_red[0][lrow];
          avb[(size_t)grow * S + c0] = f2b(al * acc[mi][0][r]);
          avb[(size_t)grow * S + c0 + 32] = f2b(al * acc[mi][1][r]);
        }
    }
    if (tid < 32) alw[row0 + tid] = s_red[0][tid];
  }
}

// ---------------- per-chunk: gate+cumsum + outer-product Mc + avT; 2 blocks/chunk
__global__ __launch_bounds__(256) void k_chunk(const ushort* __restrict__ krb,
                                               const ushort* __restrict__ avb,
                                               const float* __restrict__ knw,
                                               const float* __restrict__ alw,
                                               float* __restrict__ lcum,
                                               float* __restrict__ csum,
                                               float* __restrict__ Mc,
                                               ushort* __restrict__ avT) {
  int cid = blockIdx.x >> 1, half = blockIdx.x & 1;
  int b = cid >> 5, ch = cid & 31;
  int rbase = b * T + ch * CH;
  __shared__ float lc[CH], wts[CH];
  __shared__ float krs[CH][68], avs[CH][68];
  int tid = threadIdx.x;

  if (tid < 64) {
    float al = alw[rbase + tid], kn = knw[rbase + tid];
    float gate = al * kn * 0.1f;
    float sp = (gate > 20.f) ? gate : log1pf(expf(gate));
    float g = expf(-sp);
    float v = logf(g + 1e-8f);
#pragma unroll
    for (int off = 1; off < 64; off <<= 1) {
      float n = __shfl_up(v, off, 64);
      if (tid >= off) v += n;
    }
    lc[tid] = v;
    if (half == 0) lcum[rbase + tid] = v;
  }
  for (int i = tid; i < 512; i += 256) {
    int t = i >> 3, c8 = i & 7;
    uint4 kv = *(const uint4*)&krb[(size_t)(rbase + t) * S + c8 * 8];
    uint4 a4 = *(const uint4*)&avb[(size_t)(rbase + t) * S + c8 * 8];
    const ushort* kh = (const ushort*)&kv;
    const ushort* ah = (const ushort*)&a4;
    float kf[8], af_[8];
#pragma unroll
    for (int j = 0; j < 8; ++j) { kf[j] = b2f(kh[j]); af_[j] = b2f(ah[j]); }
    *(float4*)&krs[t][c8 * 8]     = *(const float4*)&kf[0];
    *(float4*)&krs[t][c8 * 8 + 4] = *(const float4*)&kf[4];
    *(float4*)&avs[t][c8 * 8]     = *(const float4*)&af_[0];
    *(float4*)&avs[t][c8 * 8 + 4] = *(const float4*)&af_[4];
  }
  __syncthreads();
  float tot = lc[63];
  if (tid < 64) wts[tid] = __expf(tot - lc[tid]);   // exponent <= 0
  if (tid == 63 && half == 0) csum[b * NC + ch] = tot;
  __syncthreads();
  for (int i = tid; i < 2048; i += 256) {           // this half's v-range transpose
    int v = half * 32 + (i >> 6), t = i & 63;
    avT[(size_t)(b * NC + ch) * 4096 + v * 64 + t] = f2b(avs[t][v]);
  }
  int k = tid & 63, vg = tid >> 6;
  int v0 = half * 32 + vg * 8;
  float acc[8];
#pragma unroll
  for (int j = 0; j < 8; ++j) acc[j] = 0.f;
  for (int t = 0; t < CH; ++t) {
    float kw = krs[t][k] * wts[t];
    float4 a0 = *(const float4*)&avs[t][v0];
    float4 a1 = *(const float4*)&avs[t][v0 + 4];
    acc[0] += kw * a0.x; acc[1] += kw * a0.y; acc[2] += kw * a0.z; acc[3] += kw * a0.w;
    acc[4] += kw * a1.x; acc[5] += kw * a1.y; acc[6] += kw * a1.z; acc[7] += kw * a1.w;
  }
  size_t ob = (size_t)(b * NC + ch) * 4096;
#pragma unroll
  for (int j = 0; j < 8; ++j) Mc[ob + (v0 + j) * 64 + k] = acc[j];
}

// ---------------- chunk-level scan: preloaded Mc, no dependent-load chain
__global__ __launch_bounds__(128) void k_scan(const float* __restrict__ state,
                                              const float* __restrict__ csum,
                                              const float* __restrict__ Mc,
                                              ushort* __restrict__ Scb,
                                              float* __restrict__ newstate) {
  int gid = blockIdx.x * 128 + threadIdx.x;   // B*S*S = 16384, 128 blocks
  int b = gid >> 12, e = gid & 4095;
  __shared__ float eg[NC];
  if (threadIdx.x < NC) eg[threadIdx.x] = __expf(csum[b * NC + threadIdx.x]);
  float m[NC];
#pragma unroll
  for (int c = 0; c < NC; ++c) m[c] = Mc[(size_t)(b * NC + c) * 4096 + e];
  float s = state[gid];
  __syncthreads();
#pragma unroll
  for (int c = 0; c < NC; ++c) {
    Scb[(size_t)(b * NC + c) * 4096 + e] = f2b(s);
    s = s * eg[c] + m[c];
  }
  newstate[gid] = s;
}

// ---------------- intra-chunk attention: 3 MFMA GEMMs; 2 blocks per chunk
__global__ __launch_bounds__(256) void k_attn(const ushort* __restrict__ qrb,
                                              const ushort* __restrict__ krb,
                                              const ushort* __restrict__ avT,
                                              const ushort* __restrict__ Scb,
                                              const float* __restrict__ lcum,
                                              ushort* __restrict__ retb) {
  int cid = blockIdx.x >> 1, qh = blockIdx.x & 1;
  int b = cid >> 5, ch = cid & 31;
  int rbase = b * T + ch * CH;
  size_t cb2 = (size_t)(b * NC + ch) * 4096;
  __shared__ ushort qs[32 * 64], ks_[64 * 64], vs[64 * 64], ss[64 * 64], ps[32 * 64];
  __shared__ float lcv[CH];
  int tid = threadIdx.x;
  if (tid < 64) lcv[tid] = lcum[rbase + tid];
  for (int i = tid; i < 512; i += 256) {
    int row = i >> 3, c8 = i & 7;
    int sc = (c8 ^ (row & 7)) << 3;
    *(uint4*)&ks_[row * 64 + c8 * 8] = *(const uint4*)&krb[(size_t)(rbase + row) * S + sc];
    *(uint4*)&vs[row * 64 + c8 * 8]  = *(const uint4*)&avT[cb2 + row * 64 + sc];
    *(uint4*)&ss[row * 64 + c8 * 8]  = *(const uint4*)&Scb[cb2 + row * 64 + sc];
  }
  {
    int row = tid >> 3, c8 = tid & 7;       // 32 rows x 8 chunks = 256
    int sc = (c8 ^ (row & 7)) << 3;
    *(uint4*)&qs[row * 64 + c8 * 8] = *(const uint4*)&qrb[(size_t)(rbase + qh * 32 + row) * S + sc];
  }
  __syncthreads();
  int wv = tid >> 6, l = tid & 63, lr = l >> 4, lc = l & 15;
  int tq = (wv >> 1) * 16;     // q-row base within this block's 32 rows
  int oq = (wv & 1) * 32;      // col base
  f32x4 a1[2], a2[2];
#pragma unroll
  for (int ni = 0; ni < 2; ++ni) { a1[ni] = (f32x4){0,0,0,0}; a2[ni] = (f32x4){0,0,0,0}; }

  bf16x8 qa[2];
#pragma unroll
  for (int ks = 0; ks < 2; ++ks)
    qa[ks] = *(const bf16x8*)&qs[(tq + lc) * 64 + (((ks * 4 + lr) ^ (lc & 7)) << 3)];
#pragma unroll
  for (int ni = 0; ni < 2; ++ni)
#pragma unroll
    for (int ks = 0; ks < 2; ++ks) {
      bf16x8 kf = *(const bf16x8*)&ks_[(oq + ni * 16 + lc) * 64 + (((ks * 4 + lr) ^ (lc & 7)) << 3)];
      bf16x8 sf = *(const bf16x8*)&ss[(oq + ni * 16 + lc) * 64 + (((ks * 4 + lr) ^ (lc & 7)) << 3)];
      a1[ni] = __builtin_amdgcn_mfma_f32_16x16x32_bf16(qa[ks], kf, a1[ni], 0, 0, 0);
      a2[ni] = __builtin_amdgcn_mfma_f32_16x16x32_bf16(qa[ks], sf, a2[ni], 0, 0, 0);
    }
  // P = mask(dot)*exp(sh_t - lc_s) -> ps (swizzled); a2 *= exp(sh_t)
#pragma unroll
  for (int r = 0; r < 4; ++r) {
    int prow = tq + lr * 4 + r;            // 0..31 within this block
    int trow = qh * 32 + prow;             // chunk-local 0..63
    float sh = trow ? lcv[trow - 1] : 0.f;
    float esh = __expf(sh);
#pragma unroll
    for (int ni = 0; ni < 2; ++ni) {
      int scol = oq + ni * 16 + lc;
      float pv = (scol < trow) ? a1[ni][r] * __expf(sh - lcv[scol]) : 0.f;
      ps[prow * 64 + (((scol >> 3) ^ (prow & 7)) << 3) + (scol & 7)] = f2b(pv);
      a2[ni][r] *= esh;
    }
  }
  __syncthreads();
  // GEMM3: ret += P @ avT
  bf16x8 pa[2];
#pragma unroll
  for (int ks = 0; ks < 2; ++ks)
    pa[ks] = *(const bf16x8*)&ps[(tq + lc) * 64 + (((ks * 4 + lr) ^ (lc & 7)) << 3)];
#pragma unroll
  for (int ni = 0; ni < 2; ++ni)
#pragma unroll
    for (int ks = 0; ks < 2; ++ks) {
      bf16x8 vf = *(const bf16x8*)&vs[(oq + ni * 16 + lc) * 64 + (((ks * 4 + lr) ^ (lc & 7)) << 3)];
      a2[ni] = __builtin_amdgcn_mfma_f32_16x16x32_bf16(pa[ks], vf, a2[ni], 0, 0, 0);
    }
#pragma unroll
  for (int r = 0; r < 4; ++r) {
    int trow = qh * 32 + tq + lr * 4 + r;
#pragma unroll
    for (int ni = 0; ni < 2; ++ni)
      retb[(size_t)(rbase + trow) * S + oq + ni * 16 + lc] = f2b(a2[ni][r]);
  }
}

// ---------------- output projection: bf16 MFMA, M=8192 N=1024 K=64
__global__ __launch_bounds__(256) void k_out(const ushort* __restrict__ retb,
                                             const ushort* __restrict__ Wo,
                                             const float* __restrict__ bout,
                                             float* __restrict__ out) {
  __shared__ ushort lA[64 * 64];
  __shared__ ushort lB[128 * 64];
  int tid = threadIdx.x;
  int bm0 = (blockIdx.x & 127) * 64;
  int bn0 = (blockIdx.x >> 7) * 128;
#pragma unroll
  for (int it = 0; it < 2; ++it) {
    int g = tid + it * 256, row = g >> 3, ch = g & 7;
    uint4 v = *(const uint4*)&retb[(size_t)(bm0 + row) * S + ch * 8];
    *(uint4*)&lA[row * 64 + ((ch ^ (row & 7)) * 8)] = v;
  }
#pragma unroll
  for (int it = 0; it < 4; ++it) {
    int g = tid + it * 256, row = g >> 3, ch = g & 7;
    uint4 v = *(const uint4*)&Wo[(size_t)(bn0 + row) * S + ch * 8];
    *(uint4*)&lB[row * 64 + ((ch ^ (row & 7)) * 8)] = v;
  }
  __syncthreads();
  int wv = tid >> 6, l = tid & 63, lr = l >> 4, lc = l & 15;
  int wr = wv >> 1, wc = wv & 1;
  f32x4 acc[2][4];
#pragma unroll
  for (int mi = 0; mi < 2; ++mi)
#pragma unroll
    for (int ni = 0; ni < 4; ++ni) acc[mi][ni] = (f32x4){0.f, 0.f, 0.f, 0.f};
  bf16x8 afr[2][2], bfr[4][2];
#pragma unroll
  for (int mi = 0; mi < 2; ++mi)
#pragma unroll
    for (int ks = 0; ks < 2; ++ks)
      afr[mi][ks] = *(const bf16x8*)&lA[(wr * 32 + mi * 16 + lc) * 64 + (((ks * 4 + lr) ^ (lc & 7)) * 8)];
#pragma unroll
  for (int ni = 0; ni < 4; ++ni)
#pragma unroll
    for (int ks = 0; ks < 2; ++ks)
      bfr[ni][ks] = *(const bf16x8*)&lB[(wc * 64 + ni * 16 + lc) * 64 + (((ks * 4 + lr) ^ (lc & 7)) * 8)];
#pragma unroll
  for (int ks = 0; ks < 2; ++ks)
#pragma unroll
    for (int mi = 0; mi < 2; ++mi)
#pragma unroll
      for (int ni = 0; ni < 4; ++ni)
        acc[mi][ni] = __builtin_amdgcn_mfma_f32_16x16x32_bf16(afr[mi][ks], bfr[ni][ks], acc[mi][ni], 0, 0, 0);
  float bo[4];
#pragma unroll
  for (int ni = 0; ni < 4; ++ni) bo[ni] = bout[bn0 + wc * 64 + ni * 16 + lc];
#pragma unroll
  for (int mi = 0; mi < 2; ++mi)
#pragma unroll
    for (int r = 0; r < 4; ++r) {
      int grow = bm0 + wr * 32 + mi * 16 + lr * 4 + r;
#pragma unroll
      for (int ni = 0; ni < 4; ++ni)
        out[(size_t)grow * D + bn0 + wc * 64 + ni * 16 + lc] = acc[mi][ni][r] + bo[ni];
    }
}

extern "C" void kernel_launch(void* const* d_in, const int* in_sizes, int n_in,
                              void* d_out, int out_size, void* d_ws, size_t ws_size,
                              hipStream_t stream) {
  (void)in_sizes; (void)n_in; (void)out_size; (void)ws_size;
  const float* x     = (const float*)d_in[0];
  const float* state = (const float*)d_in[1];
  const float* Wk    = (const float*)d_in[2];
  const float* Wv    = (const float*)d_in[3];
  const float* Wq    = (const float*)d_in[4];
  const float* Wout  = (const float*)d_in[5];
  const float* bout  = (const float*)d_in[6];
  const float* Wg    = (const float*)d_in[7];
  const float* bg    = (const float*)d_in[8];
  const float* cosT  = (const float*)d_in[9];
  const float* sinT  = (const float*)d_in[10];

  float* out = (float*)d_out;
  float* newstate = out + (size_t)B * T * D;

  const int NTOK = B * T;            // 8192
  const int NE = B * T * S;          // 524288
  ushort* Wt   = (ushort*)d_ws;      // 262144
  ushort* Wo   = Wt + 262144;        // 65536
  ushort* qrb  = Wo + 65536;
  ushort* krb  = qrb + NE;
  ushort* avb  = krb + NE;
  ushort* avT  = avb + NE;
  ushort* Scb  = avT + NE;           // B*NC*4096 = NE
  ushort* retb = Scb + NE;
  float* knw   = (float*)(retb + NE);
  float* alw   = knw + NTOK;
  float* lcum  = alw + NTOK;
  float* csum  = lcum + NTOK;        // B*NC
  float* Mc    = csum + B * NC;      // NE floats

  hipLaunchKernelGGL(k_prep, dim3(1280), dim3(256), 0, stream, Wk, Wv, Wq, Wg, Wout, Wt, Wo);
  hipLaunchKernelGGL(k_proj, dim3(NTOK / 32 * 2), dim3(256), 0, stream, x, Wt, cosT, sinT, bg, qrb, krb, avb, knw, alw);
  hipLaunchKernelGGL(k_chunk, dim3(B * NC * 2), dim3(256), 0, stream, krb, avb, knw, alw, lcum, csum, Mc, avT);
  hipLaunchKernelGGL(k_scan, dim3(B * S * S / 128), dim3(128), 0, stream, state, csum, Mc, Scb, newstate);
  hipLaunchKernelGGL(k_attn, dim3(B * NC * 2), dim3(256), 0, stream, qrb, krb, avT, Scb, lcum, retb);
  hipLaunchKernelGGL(k_out, dim3((NTOK / 64) * (D / 128)), dim3(256), 0, stream, retb, Wo, bout, out);
}

// Round 6
// 49.803 us; speedup vs baseline: 5.8708x; 1.1093x over previous
//
#include <hip/hip_runtime.h>
#include <math.h>

#define B 4
#define T 2048
#define D 1024
#define S 64
#define NC 32      // chunks per batch
#define CH 64      // chunk length

typedef float f32x4 __attribute__((ext_vector_type(4)));
typedef short bf16x8 __attribute__((ext_vector_type(8)));

__device__ inline ushort f2b(float f) {   // fp32 -> bf16 RNE
  unsigned u = __float_as_uint(f);
  u += 0x7fff + ((u >> 16) & 1);
  return (ushort)(u >> 16);
}
__device__ inline float b2f(ushort h) { return __uint_as_float(((unsigned)h) << 16); }

__device__ inline void gll16(const ushort* g, ushort* l) {
  __builtin_amdgcn_global_load_lds((const __attribute__((address_space(1))) void*)g,
                                   (__attribute__((address_space(3))) void*)l, 16, 0, 0);
}

// ---------------- weights -> bf16. Column order: k 0-63 | q 64-127 | v 128-191 | gate 192
__global__ __launch_bounds__(256) void k_prep(const float* __restrict__ Wk,
                                              const float* __restrict__ Wv,
                                              const float* __restrict__ Wq,
                                              const float* __restrict__ Wg,
                                              const float* __restrict__ Wout,
                                              ushort* __restrict__ Wt,
                                              ushort* __restrict__ Wo) {
  int idx = blockIdx.x * 256 + threadIdx.x;
  if (idx < 256 * 1024) {
    int c = idx >> 10, kk = idx & 1023;
    float v = 0.f;
    if (c < 64)        v = Wk[c * D + kk];
    else if (c < 128)  v = Wq[(c - 64) * D + kk];
    else if (c < 192)  v = Wv[(c - 128) * D + kk];
    else if (c == 192) v = Wg[kk];
    Wt[idx] = f2b(v);
  } else {
    int j = idx - 256 * 1024;
    if (j < D * S) Wo[j] = f2b(Wout[j]);
  }
}

// ---------------- bf16-MFMA projection, BM=32 BN=128, grid 512 (2 blocks/CU)
// XCD-paired: (mt,cb=0) and (mt,cb=1) differ by 8 in blockIdx -> same XCD L2,
// so the shared 128KB x tile is fetched from HBM once per pair.
__global__ __launch_bounds__(256) void k_proj(const float* __restrict__ x,
                                              const ushort* __restrict__ Wt,
                                              const float* __restrict__ cosT,
                                              const float* __restrict__ sinT,
                                              const float* __restrict__ bgp,
                                              ushort* __restrict__ qrb,
                                              ushort* __restrict__ krb,
                                              ushort* __restrict__ avb,
                                              float* __restrict__ knw,
                                              float* __restrict__ alw) {
  __shared__ ushort lA[2][32 * 64];    // 4KB x2
  __shared__ ushort lB[2][128 * 64];   // 16KB x2
  __shared__ float s_red[2][32];
  int tid = threadIdx.x;
  int bid = blockIdx.x;
  int mt = (bid >> 4) * 8 + (bid & 7), cb = (bid >> 3) & 1;
  int row0 = mt * 32, col0 = cb * 128;
  int wv = tid >> 6, l = tid & 63, lr = l >> 4, lc = l & 15;
  int arow = tid >> 3, ac8 = tid & 7;
  int gr_l = l >> 3, gc8 = l & 7;
  const float* xrow = &x[(size_t)(row0 + arow) * D + ((ac8 ^ (arow & 7)) << 3)];
  int f0 = ((wv >> 1) << 2) | (wv & 1);   // wave's first n-frag; pair is f0+2

  f32x4 acc[2][2];
#pragma unroll
  for (int mi = 0; mi < 2; ++mi)
#pragma unroll
    for (int ni = 0; ni < 2; ++ni) acc[mi][ni] = (f32x4){0.f, 0.f, 0.f, 0.f};

  float af[8];
  // prologue: tile 0 -> buf 0
  {
    *(float4*)&af[0] = *(const float4*)&xrow[0];
    *(float4*)&af[4] = *(const float4*)&xrow[4];
#pragma unroll
    for (int j = 0; j < 4; ++j) {
      int rloc = wv * 32 + j * 8 + gr_l;
      gll16(&Wt[(size_t)(col0 + rloc) * D + ((gc8 ^ (rloc & 7)) << 3)],
            (ushort*)&lB[0][(wv * 32 + j * 8) * 64]);
    }
    union { ushort h[8]; uint4 v; } u;
#pragma unroll
    for (int j = 0; j < 8; ++j) u.h[j] = f2b(af[j]);
    *(uint4*)&lA[0][arow * 64 + (ac8 << 3)] = u.v;
  }
  __syncthreads();

  const int NT = D / 64;
  for (int t = 0; t < NT; ++t) {
    int p = t & 1;
    if (t + 1 < NT) {
      int kc = (t + 1) * 64;
      *(float4*)&af[0] = *(const float4*)&xrow[kc];
      *(float4*)&af[4] = *(const float4*)&xrow[kc + 4];
#pragma unroll
      for (int j = 0; j < 4; ++j) {
        int rloc = wv * 32 + j * 8 + gr_l;
        gll16(&Wt[(size_t)(col0 + rloc) * D + kc + ((gc8 ^ (rloc & 7)) << 3)],
              (ushort*)&lB[p ^ 1][(wv * 32 + j * 8) * 64]);
      }
    }
    bf16x8 afr[2][2], bfr[2][2];
#pragma unroll
    for (int mi = 0; mi < 2; ++mi)
#pragma unroll
      for (int ks = 0; ks < 2; ++ks)
        afr[mi][ks] = *(const bf16x8*)&lA[p][(mi * 16 + lc) * 64 + (((ks * 4 + lr) ^ (lc & 7)) << 3)];
#pragma unroll
    for (int ni = 0; ni < 2; ++ni)
#pragma unroll
      for (int ks = 0; ks < 2; ++ks)
        bfr[ni][ks] = *(const bf16x8*)&lB[p][((f0 + 2 * ni) * 16 + lc) * 64 + (((ks * 4 + lr) ^ (lc & 7)) << 3)];
#pragma unroll
    for (int ks = 0; ks < 2; ++ks)
#pragma unroll
      for (int mi = 0; mi < 2; ++mi)
#pragma unroll
        for (int ni = 0; ni < 2; ++ni)
          acc[mi][ni] = __builtin_amdgcn_mfma_f32_16x16x32_bf16(afr[mi][ks], bfr[ni][ks], acc[mi][ni], 0, 0, 0);
    if (t + 1 < NT) {
      union { ushort h[8]; uint4 v; } u;
#pragma unroll
      for (int j = 0; j < 8; ++j) u.h[j] = f2b(af[j]);
      *(uint4*)&lA[p ^ 1][arow * 64 + (ac8 << 3)] = u.v;
    }
    __syncthreads();
  }

  // epilogue. C/D map: row = mi*16+lr*4+r, col(frag f) = f*16+lc.
  float bgv = bgp[0];
  int c0 = (wv & 1) * 16 + lc;   // col within the 64-wide group; partner c0+32
  if (cb == 0) {
    ushort* dst = (wv < 2) ? krb : qrb;
#pragma unroll
    for (int mi = 0; mi < 2; ++mi)
#pragma unroll
      for (int r = 0; r < 4; ++r) {
        int lrow = mi * 16 + lr * 4 + r;
        int grow = row0 + lrow;
        int tt = grow & (T - 1);
        float a0 = acc[mi][0][r], a1 = acc[mi][1][r];
        float cv0 = cosT[tt * S + c0], sv0 = sinT[tt * S + c0];
        float cv1 = cosT[tt * S + c0 + 32], sv1 = sinT[tt * S + c0 + 32];
        float o0 = a0 * cv0 - a1 * sv0;
        float o1 = a1 * cv1 + a0 * sv1;
        dst[(size_t)grow * S + c0] = f2b(o0);
        dst[(size_t)grow * S + c0 + 32] = f2b(o1);
        if (wv < 2) {
          float nrm = o0 * o0 + o1 * o1;
#pragma unroll
          for (int off = 1; off < 16; off <<= 1) nrm += __shfl_xor(nrm, off, 64);
          if (lc == 0) s_red[wv][lrow] = nrm;
        }
      }
    __syncthreads();
    if (tid < 32) knw[row0 + tid] = s_red[0][tid] + s_red[1][tid];
  } else {
    if (wv == 2 && lc == 0) {    // gate = local col 64 = frag 4, lc==0
#pragma unroll
      for (int mi = 0; mi < 2; ++mi)
#pragma unroll
        for (int r = 0; r < 4; ++r) {
          int lrow = mi * 16 + lr * 4 + r;
          s_red[0][lrow] = 1.f / (1.f + __expf(-(acc[mi][0][r] + bgv)));
        }
    }
    __syncthreads();
    if (wv < 2) {
#pragma unroll
      for (int mi = 0; mi < 2; ++mi)
#pragma unroll
        for (int r = 0; r < 4; ++r) {
          int lrow = mi * 16 + lr * 4 + r, grow = row0 + lrow;
          float al = s_red[0][lrow];
          avb[(size_t)grow * S + c0] = f2b(al * acc[mi][0][r]);
          avb[(size_t)grow * S + c0 + 32] = f2b(al * acc[mi][1][r]);
        }
    }
    if (tid < 32) alw[row0 + tid] = s_red[0][tid];
  }
}

// ---------------- per-chunk: gate+cumsum + outer-product Mc + avT; 2 blocks/chunk (XCD-paired)
__global__ __launch_bounds__(256) void k_chunk(const ushort* __restrict__ krb,
                                               const ushort* __restrict__ avb,
                                               const float* __restrict__ knw,
                                               const float* __restrict__ alw,
                                               float* __restrict__ lcum,
                                               float* __restrict__ csum,
                                               float* __restrict__ Mc,
                                               ushort* __restrict__ avT) {
  int bid = blockIdx.x;
  int cid = (bid >> 4) * 8 + (bid & 7), half = (bid >> 3) & 1;
  int b = cid >> 5, ch = cid & 31;
  int rbase = b * T + ch * CH;
  __shared__ float lc[CH], wts[CH];
  __shared__ float krs[CH][68], avs[CH][68];
  int tid = threadIdx.x;

  if (tid < 64) {
    float al = alw[rbase + tid], kn = knw[rbase + tid];
    float gate = al * kn * 0.1f;
    float sp = (gate > 20.f) ? gate : log1pf(expf(gate));
    float g = expf(-sp);
    float v = logf(g + 1e-8f);
#pragma unroll
    for (int off = 1; off < 64; off <<= 1) {
      float n = __shfl_up(v, off, 64);
      if (tid >= off) v += n;
    }
    lc[tid] = v;
    if (half == 0) lcum[rbase + tid] = v;
  }
  for (int i = tid; i < 512; i += 256) {
    int t = i >> 3, c8 = i & 7;
    uint4 kv = *(const uint4*)&krb[(size_t)(rbase + t) * S + c8 * 8];
    uint4 a4 = *(const uint4*)&avb[(size_t)(rbase + t) * S + c8 * 8];
    const ushort* kh = (const ushort*)&kv;
    const ushort* ah = (const ushort*)&a4;
    float kf[8], af_[8];
#pragma unroll
    for (int j = 0; j < 8; ++j) { kf[j] = b2f(kh[j]); af_[j] = b2f(ah[j]); }
    *(float4*)&krs[t][c8 * 8]     = *(const float4*)&kf[0];
    *(float4*)&krs[t][c8 * 8 + 4] = *(const float4*)&kf[4];
    *(float4*)&avs[t][c8 * 8]     = *(const float4*)&af_[0];
    *(float4*)&avs[t][c8 * 8 + 4] = *(const float4*)&af_[4];
  }
  __syncthreads();
  float tot = lc[63];
  if (tid < 64) wts[tid] = __expf(tot - lc[tid]);   // exponent <= 0
  if (tid == 63 && half == 0) csum[b * NC + ch] = tot;
  __syncthreads();
  for (int i = tid; i < 2048; i += 256) {           // this half's v-range transpose
    int v = half * 32 + (i >> 6), t = i & 63;
    avT[(size_t)(b * NC + ch) * 4096 + v * 64 + t] = f2b(avs[t][v]);
  }
  int k = tid & 63, vg = tid >> 6;
  int v0 = half * 32 + vg * 8;
  float acc[8];
#pragma unroll
  for (int j = 0; j < 8; ++j) acc[j] = 0.f;
  for (int t = 0; t < CH; ++t) {
    float kw = krs[t][k] * wts[t];
    float4 a0 = *(const float4*)&avs[t][v0];
    float4 a1 = *(const float4*)&avs[t][v0 + 4];
    acc[0] += kw * a0.x; acc[1] += kw * a0.y; acc[2] += kw * a0.z; acc[3] += kw * a0.w;
    acc[4] += kw * a1.x; acc[5] += kw * a1.y; acc[6] += kw * a1.z; acc[7] += kw * a1.w;
  }
  size_t ob = (size_t)(b * NC + ch) * 4096;
#pragma unroll
  for (int j = 0; j < 8; ++j) Mc[ob + (v0 + j) * 64 + k] = acc[j];
}

// ---------------- chunk-level scan: preloaded Mc; 256 blocks x 64 threads
__global__ __launch_bounds__(64) void k_scan(const float* __restrict__ state,
                                             const float* __restrict__ csum,
                                             const float* __restrict__ Mc,
                                             ushort* __restrict__ Scb,
                                             float* __restrict__ newstate) {
  int gid = blockIdx.x * 64 + threadIdx.x;   // B*S*S = 16384
  int b = gid >> 12, e = gid & 4095;
  __shared__ float eg[NC];
  if (threadIdx.x < NC) eg[threadIdx.x] = __expf(csum[b * NC + threadIdx.x]);
  float m[NC];
#pragma unroll
  for (int c = 0; c < NC; ++c) m[c] = Mc[(size_t)(b * NC + c) * 4096 + e];
  float s = state[gid];
  __syncthreads();
#pragma unroll
  for (int c = 0; c < NC; ++c) {
    Scb[(size_t)(b * NC + c) * 4096 + e] = f2b(s);
    s = s * eg[c] + m[c];
  }
  newstate[gid] = s;
}

// ---------------- fused intra-chunk attention + output GEMM
// grid 256 = (chunk, n-half), XCD-paired so both halves share the chunk's K/V/S/q
// tiles via L2. Attn (3 small GEMMs) is duplicated per half (cheap); ret stays in
// LDS as the A-operand of the out-GEMM; Wout B-frags are read directly from global.
__global__ __launch_bounds__(256) void k_ao(const ushort* __restrict__ qrb,
                                            const ushort* __restrict__ krb,
                                            const ushort* __restrict__ avT,
                                            const ushort* __restrict__ Scb,
                                            const float* __restrict__ lcum,
                                            const ushort* __restrict__ Wo,
                                            const float* __restrict__ bout,
                                            float* __restrict__ out) {
  int bid = blockIdx.x;
  int cid = (bid >> 4) * 8 + (bid & 7), nh = (bid >> 3) & 1;
  int b = cid >> 5, ch = cid & 31;
  int rbase = b * T + ch * CH;
  size_t cb2 = (size_t)(b * NC + ch) * 4096;
  __shared__ ushort qs[64 * 64], ks_[64 * 64], vs[64 * 64], ss[64 * 64], ps[64 * 64];
  __shared__ float lcv[CH];
  int tid = threadIdx.x;
  if (tid < 64) lcv[tid] = lcum[rbase + tid];
  for (int i = tid; i < 512; i += 256) {
    int row = i >> 3, c8 = i & 7;
    int sc = (c8 ^ (row & 7)) << 3;
    *(uint4*)&qs[row * 64 + c8 * 8]  = *(const uint4*)&qrb[(size_t)(rbase + row) * S + sc];
    *(uint4*)&ks_[row * 64 + c8 * 8] = *(const uint4*)&krb[(size_t)(rbase + row) * S + sc];
    *(uint4*)&vs[row * 64 + c8 * 8]  = *(const uint4*)&avT[cb2 + row * 64 + sc];
    *(uint4*)&ss[row * 64 + c8 * 8]  = *(const uint4*)&Scb[cb2 + row * 64 + sc];
  }
  __syncthreads();
  int wv = tid >> 6, l = tid & 63, lr = l >> 4, lc = l & 15;
  int tq = wv * 16;            // wave owns q-rows tq..tq+15
  f32x4 a1[4], a2[4];
#pragma unroll
  for (int ni = 0; ni < 4; ++ni) { a1[ni] = (f32x4){0,0,0,0}; a2[ni] = (f32x4){0,0,0,0}; }

  bf16x8 qa[2];
#pragma unroll
  for (int ks = 0; ks < 2; ++ks)
    qa[ks] = *(const bf16x8*)&qs[(tq + lc) * 64 + (((ks * 4 + lr) ^ (lc & 7)) << 3)];
#pragma unroll
  for (int ni = 0; ni < 4; ++ni)
#pragma unroll
    for (int ks = 0; ks < 2; ++ks) {
      bf16x8 kf = *(const bf16x8*)&ks_[(ni * 16 + lc) * 64 + (((ks * 4 + lr) ^ (lc & 7)) << 3)];
      bf16x8 sf = *(const bf16x8*)&ss[(ni * 16 + lc) * 64 + (((ks * 4 + lr) ^ (lc & 7)) << 3)];
      a1[ni] = __builtin_amdgcn_mfma_f32_16x16x32_bf16(qa[ks], kf, a1[ni], 0, 0, 0);
      a2[ni] = __builtin_amdgcn_mfma_f32_16x16x32_bf16(qa[ks], sf, a2[ni], 0, 0, 0);
    }
  // P = mask(dot)*exp(sh_t - lc_s) -> ps (swizzled); a2 *= exp(sh_t)
#pragma unroll
  for (int r = 0; r < 4; ++r) {
    int trow = tq + lr * 4 + r;
    float sh = trow ? lcv[trow - 1] : 0.f;
    float esh = __expf(sh);
#pragma unroll
    for (int ni = 0; ni < 4; ++ni) {
      int scol = ni * 16 + lc;
      float pv = (scol < trow) ? a1[ni][r] * __expf(sh - lcv[scol]) : 0.f;
      ps[trow * 64 + (((scol >> 3) ^ (trow & 7)) << 3) + (scol & 7)] = f2b(pv);
      a2[ni][r] *= esh;
    }
  }
  __syncthreads();
  // GEMM3: ret += P @ avT
  bf16x8 pa[2];
#pragma unroll
  for (int ks = 0; ks < 2; ++ks)
    pa[ks] = *(const bf16x8*)&ps[(tq + lc) * 64 + (((ks * 4 + lr) ^ (lc & 7)) << 3)];
#pragma unroll
  for (int ni = 0; ni < 4; ++ni)
#pragma unroll
    for (int ks = 0; ks < 2; ++ks) {
      bf16x8 vf = *(const bf16x8*)&vs[(ni * 16 + lc) * 64 + (((ks * 4 + lr) ^ (lc & 7)) << 3)];
      a2[ni] = __builtin_amdgcn_mfma_f32_16x16x32_bf16(pa[ks], vf, a2[ni], 0, 0, 0);
    }
  // write ret (bf16) into ks_ as the out-GEMM A tile (swizzled rows)
#pragma unroll
  for (int r = 0; r < 4; ++r) {
    int trow = tq + lr * 4 + r;
#pragma unroll
    for (int ni = 0; ni < 4; ++ni) {
      int scol = ni * 16 + lc;
      ks_[trow * 64 + (((scol >> 3) ^ (trow & 7)) << 3) + (scol & 7)] = f2b(a2[ni][r]);
    }
  }
  __syncthreads();

  // ---------- out-GEMM: M=64 (chunk tokens) x N=512 (this half) x K=64
  bf16x8 afr[4][2];
#pragma unroll
  for (int mi = 0; mi < 4; ++mi)
#pragma unroll
    for (int ks = 0; ks < 2; ++ks)
      afr[mi][ks] = *(const bf16x8*)&ks_[(mi * 16 + lc) * 64 + (((ks * 4 + lr) ^ (lc & 7)) << 3)];

  int colw = nh * 512 + wv * 32;   // wave's first col within group g: colw + g*128
  bf16x8 bw[2][4];
#pragma unroll
  for (int ni = 0; ni < 2; ++ni)
#pragma unroll
    for (int ks = 0; ks < 2; ++ks)
      bw[0][ni * 2 + ks] = *(const bf16x8*)&Wo[(size_t)(colw + ni * 16 + lc) * 64 + (ks * 4 + lr) * 8];

  for (int g = 0; g < 4; ++g) {
    int p = g & 1;
    if (g + 1 < 4) {
      int colg = colw + (g + 1) * 128;
#pragma unroll
      for (int ni = 0; ni < 2; ++ni)
#pragma unroll
        for (int ks = 0; ks < 2; ++ks)
          bw[p ^ 1][ni * 2 + ks] = *(const bf16x8*)&Wo[(size_t)(colg + ni * 16 + lc) * 64 + (ks * 4 + lr) * 8];
    }
    f32x4 acc[4][2];
#pragma unroll
    for (int mi = 0; mi < 4; ++mi)
#pragma unroll
      for (int ni = 0; ni < 2; ++ni) acc[mi][ni] = (f32x4){0.f, 0.f, 0.f, 0.f};
#pragma unroll
    for (int ks = 0; ks < 2; ++ks)
#pragma unroll
      for (int mi = 0; mi < 4; ++mi)
#pragma unroll
        for (int ni = 0; ni < 2; ++ni)
          acc[mi][ni] = __builtin_amdgcn_mfma_f32_16x16x32_bf16(afr[mi][ks], bw[p][ni * 2 + ks], acc[mi][ni], 0, 0, 0);
    float bo[2];
#pragma unroll
    for (int ni = 0; ni < 2; ++ni) bo[ni] = bout[colw + g * 128 + ni * 16 + lc];
#pragma unroll
    for (int mi = 0; mi < 4; ++mi)
#pragma unroll
      for (int r = 0; r < 4; ++r) {
        int grow = rbase + mi * 16 + lr * 4 + r;
#pragma unroll
        for (int ni = 0; ni < 2; ++ni)
          out[(size_t)grow * D + colw + g * 128 + ni * 16 + lc] = acc[mi][ni][r] + bo[ni];
      }
  }
}

extern "C" void kernel_launch(void* const* d_in, const int* in_sizes, int n_in,
                              void* d_out, int out_size, void* d_ws, size_t ws_size,
                              hipStream_t stream) {
  (void)in_sizes; (void)n_in; (void)out_size; (void)ws_size;
  const float* x     = (const float*)d_in[0];
  const float* state = (const float*)d_in[1];
  const float* Wk    = (const float*)d_in[2];
  const float* Wv    = (const float*)d_in[3];
  const float* Wq    = (const float*)d_in[4];
  const float* Wout  = (const float*)d_in[5];
  const float* bout  = (const float*)d_in[6];
  const float* Wg    = (const float*)d_in[7];
  const float* bg    = (const float*)d_in[8];
  const float* cosT  = (const float*)d_in[9];
  const float* sinT  = (const float*)d_in[10];

  float* out = (float*)d_out;
  float* newstate = out + (size_t)B * T * D;

  const int NTOK = B * T;            // 8192
  const int NE = B * T * S;          // 524288
  ushort* Wt   = (ushort*)d_ws;      // 262144
  ushort* Wo   = Wt + 262144;        // 65536
  ushort* qrb  = Wo + 65536;
  ushort* krb  = qrb + NE;
  ushort* avb  = krb + NE;
  ushort* avT  = avb + NE;
  ushort* Scb  = avT + NE;           // B*NC*4096 = NE
  float* knw   = (float*)(Scb + NE);
  float* alw   = knw + NTOK;
  float* lcum  = alw + NTOK;
  float* csum  = lcum + NTOK;        // B*NC
  float* Mc    = csum + B * NC;      // NE floats

  hipLaunchKernelGGL(k_prep, dim3(1280), dim3(256), 0, stream, Wk, Wv, Wq, Wg, Wout, Wt, Wo);
  hipLaunchKernelGGL(k_proj, dim3(NTOK / 32 * 2), dim3(256), 0, stream, x, Wt, cosT, sinT, bg, qrb, krb, avb, knw, alw);
  hipLaunchKernelGGL(k_chunk, dim3(B * NC * 2), dim3(256), 0, stream, krb, avb, knw, alw, lcum, csum, Mc, avT);
  hipLaunchKernelGGL(k_scan, dim3(B * S * S / 64), dim3(64), 0, stream, state, csum, Mc, Scb, newstate);
  hipLaunchKernelGGL(k_ao, dim3(B * NC * 2), dim3(256), 0, stream, qrb, krb, avT, Scb, lcum, Wo, bout, out);
}

// Round 7
// 48.010 us; speedup vs baseline: 6.0900x; 1.0373x over previous
//
#include <hip/hip_runtime.h>
#include <math.h>

#define B 4
#define T 2048
#define D 1024
#define S 64
#define NC 32      // chunks per batch
#define CH 64      // chunk length

typedef float f32x4 __attribute__((ext_vector_type(4)));
typedef short bf16x8 __attribute__((ext_vector_type(8)));

__device__ inline ushort f2b(float f) {   // fp32 -> bf16 RNE
  unsigned u = __float_as_uint(f);
  u += 0x7fff + ((u >> 16) & 1);
  return (ushort)(u >> 16);
}
__device__ inline float b2f(ushort h) { return __uint_as_float(((unsigned)h) << 16); }

__device__ inline void gll16(const ushort* g, ushort* l) {
  __builtin_amdgcn_global_load_lds((const __attribute__((address_space(1))) void*)g,
                                   (__attribute__((address_space(3))) void*)l, 16, 0, 0);
}

// ---------------- weights -> bf16. Column order: k 0-63 | q 64-127 | v 128-191 | gate 192
__global__ __launch_bounds__(256) void k_prep(const float* __restrict__ Wk,
                                              const float* __restrict__ Wv,
                                              const float* __restrict__ Wq,
                                              const float* __restrict__ Wg,
                                              const float* __restrict__ Wout,
                                              ushort* __restrict__ Wt,
                                              ushort* __restrict__ Wo) {
  int idx = blockIdx.x * 256 + threadIdx.x;
  if (idx < 256 * 1024) {
    int c = idx >> 10, kk = idx & 1023;
    float v = 0.f;
    if (c < 64)        v = Wk[c * D + kk];
    else if (c < 128)  v = Wq[(c - 64) * D + kk];
    else if (c < 192)  v = Wv[(c - 128) * D + kk];
    else if (c == 192) v = Wg[kk];
    Wt[idx] = f2b(v);
  } else {
    int j = idx - 256 * 1024;
    if (j < D * S) Wo[j] = f2b(Wout[j]);
  }
}

// ---------------- bf16-MFMA projection, BM=32 BN=128 BK=128, grid 512 (2 blocks/CU)
// XCD-paired: (mt,cb=0)/(mt,cb=1) share the x tile via one XCD's L2.
__global__ __launch_bounds__(256) void k_proj(const float* __restrict__ x,
                                              const ushort* __restrict__ Wt,
                                              const float* __restrict__ cosT,
                                              const float* __restrict__ sinT,
                                              const float* __restrict__ bgp,
                                              ushort* __restrict__ qrb,
                                              ushort* __restrict__ krb,
                                              ushort* __restrict__ avb,
                                              float* __restrict__ knw,
                                              float* __restrict__ alw) {
  __shared__ ushort lA[2][32 * 128];    // 8KB x2
  __shared__ ushort lB[2][128 * 128];   // 32KB x2   (total 80KB -> 2 blocks/CU)
  int tid = threadIdx.x;
  int bid = blockIdx.x;
  int mt = (bid >> 4) * 8 + (bid & 7), cb = (bid >> 3) & 1;
  int row0 = mt * 32, col0 = cb * 128;
  int wv = tid >> 6, l = tid & 63, lr = l >> 4, lc = l & 15;
  int arow = tid >> 4, ac16 = tid & 15;
  int asw = (ac16 ^ (arow & 7)) << 3;
  const float* xr0 = &x[(size_t)(row0 + arow) * D + asw];
  const float* xr1 = &x[(size_t)(row0 + arow + 16) * D + asw];   // (arow+16)&7 == arow&7
  int gr4 = l >> 4, gc16 = l & 15;
  int f0 = ((wv >> 1) << 2) | (wv & 1);   // wave's first n-frag; RoPE pair is f0+2

  f32x4 acc[2][2];
#pragma unroll
  for (int mi = 0; mi < 2; ++mi)
#pragma unroll
    for (int ni = 0; ni < 2; ++ni) acc[mi][ni] = (f32x4){0.f, 0.f, 0.f, 0.f};

  float af0[8], af1[8];
  // ---- prologue: tile 0 -> buf 0
  {
    *(float4*)&af0[0] = *(const float4*)&xr0[0];
    *(float4*)&af0[4] = *(const float4*)&xr0[4];
    *(float4*)&af1[0] = *(const float4*)&xr1[0];
    *(float4*)&af1[4] = *(const float4*)&xr1[4];
#pragma unroll
    for (int j = 0; j < 8; ++j) {
      int rloc = wv * 32 + j * 4 + gr4;
      gll16(&Wt[(size_t)(col0 + rloc) * D + ((gc16 ^ (rloc & 7)) << 3)],
            (ushort*)&lB[0][(wv * 32 + j * 4) * 128]);
    }
    union { ushort h[8]; uint4 v; } u0, u1;
#pragma unroll
    for (int j = 0; j < 8; ++j) { u0.h[j] = f2b(af0[j]); u1.h[j] = f2b(af1[j]); }
    *(uint4*)&lA[0][arow * 128 + ac16 * 8] = u0.v;
    *(uint4*)&lA[0][(arow + 16) * 128 + ac16 * 8] = u1.v;
  }
  __syncthreads();

  const int NT = D / 128;
  for (int t = 0; t < NT; ++t) {
    int p = t & 1;
    if (t + 1 < NT) {
      int kc = (t + 1) * 128;
      *(float4*)&af0[0] = *(const float4*)&xr0[kc];
      *(float4*)&af0[4] = *(const float4*)&xr0[kc + 4];
      *(float4*)&af1[0] = *(const float4*)&xr1[kc];
      *(float4*)&af1[4] = *(const float4*)&xr1[kc + 4];
#pragma unroll
      for (int j = 0; j < 8; ++j) {
        int rloc = wv * 32 + j * 4 + gr4;
        gll16(&Wt[(size_t)(col0 + rloc) * D + kc + ((gc16 ^ (rloc & 7)) << 3)],
              (ushort*)&lB[p ^ 1][(wv * 32 + j * 4) * 128]);
      }
    }
    bf16x8 afr[2][4], bfr[2][4];
#pragma unroll
    for (int mi = 0; mi < 2; ++mi)
#pragma unroll
      for (int ks = 0; ks < 4; ++ks)
        afr[mi][ks] = *(const bf16x8*)&lA[p][(mi * 16 + lc) * 128 + (((ks * 4 + lr) ^ (lc & 7)) << 3)];
#pragma unroll
    for (int ni = 0; ni < 2; ++ni)
#pragma unroll
      for (int ks = 0; ks < 4; ++ks)
        bfr[ni][ks] = *(const bf16x8*)&lB[p][((f0 + 2 * ni) * 16 + lc) * 128 + (((ks * 4 + lr) ^ (lc & 7)) << 3)];
#pragma unroll
    for (int ks = 0; ks < 4; ++ks)
#pragma unroll
      for (int mi = 0; mi < 2; ++mi)
#pragma unroll
        for (int ni = 0; ni < 2; ++ni)
          acc[mi][ni] = __builtin_amdgcn_mfma_f32_16x16x32_bf16(afr[mi][ks], bfr[ni][ks], acc[mi][ni], 0, 0, 0);
    if (t + 1 < NT) {
      union { ushort h[8]; uint4 v; } u0, u1;
#pragma unroll
      for (int j = 0; j < 8; ++j) { u0.h[j] = f2b(af0[j]); u1.h[j] = f2b(af1[j]); }
      *(uint4*)&lA[p ^ 1][arow * 128 + ac16 * 8] = u0.v;
      *(uint4*)&lA[p ^ 1][(arow + 16) * 128 + ac16 * 8] = u1.v;
    }
    __syncthreads();
  }

  // epilogue. C/D map: row = mi*16+lr*4+r, col(frag f) = f*16+lc.
  float (*s_red)[32] = (float (*)[32])(&lA[0][0]);   // alias dead lA (keeps LDS at 80KB)
  float bgv = bgp[0];
  int c0 = (wv & 1) * 16 + lc;   // col within the 64-wide group; partner c0+32
  if (cb == 0) {
    ushort* dst = (wv < 2) ? krb : qrb;
#pragma unroll
    for (int mi = 0; mi < 2; ++mi)
#pragma unroll
      for (int r = 0; r < 4; ++r) {
        int lrow = mi * 16 + lr * 4 + r;
        int grow = row0 + lrow;
        int tt = grow & (T - 1);
        float a0 = acc[mi][0][r], a1 = acc[mi][1][r];
        float cv0 = cosT[tt * S + c0], sv0 = sinT[tt * S + c0];
        float cv1 = cosT[tt * S + c0 + 32], sv1 = sinT[tt * S + c0 + 32];
        float o0 = a0 * cv0 - a1 * sv0;
        float o1 = a1 * cv1 + a0 * sv1;
        dst[(size_t)grow * S + c0] = f2b(o0);
        dst[(size_t)grow * S + c0 + 32] = f2b(o1);
        if (wv < 2) {
          float nrm = o0 * o0 + o1 * o1;
#pragma unroll
          for (int off = 1; off < 16; off <<= 1) nrm += __shfl_xor(nrm, off, 64);
          if (lc == 0) s_red[wv][lrow] = nrm;
        }
      }
    __syncthreads();
    if (tid < 32) knw[row0 + tid] = s_red[0][tid] + s_red[1][tid];
  } else {
    if (wv == 2 && lc == 0) {    // gate = local col 64 = frag 4, lc==0
#pragma unroll
      for (int mi = 0; mi < 2; ++mi)
#pragma unroll
        for (int r = 0; r < 4; ++r) {
          int lrow = mi * 16 + lr * 4 + r;
          s_red[0][lrow] = 1.f / (1.f + __expf(-(acc[mi][0][r] + bgv)));
        }
    }
    __syncthreads();
    if (wv < 2) {
#pragma unroll
      for (int mi = 0; mi < 2; ++mi)
#pragma unroll
        for (int r = 0; r < 4; ++r) {
          int lrow = mi * 16 + lr * 4 + r, grow = row0 + lrow;
          float al = s_red[0][lrow];
          avb[(size_t)grow * S + c0] = f2b(al * acc[mi][0][r]);
          avb[(size_t)grow * S + c0 + 32] = f2b(al * acc[mi][1][r]);
        }
    }
    if (tid < 32) alw[row0 + tid] = s_red[0][tid];
  }
}

// ---------------- per-chunk: gate+cumsum + outer-product Mc + avT; 2 blocks/chunk (XCD-paired)
__global__ __launch_bounds__(256) void k_chunk(const ushort* __restrict__ krb,
                                               const ushort* __restrict__ avb,
                                               const float* __restrict__ knw,
                                               const float* __restrict__ alw,
                                               float* __restrict__ lcum,
                                               float* __restrict__ csum,
                                               float* __restrict__ Mc,
                                               ushort* __restrict__ avT) {
  int bid = blockIdx.x;
  int cid = (bid >> 4) * 8 + (bid & 7), half = (bid >> 3) & 1;
  int b = cid >> 5, ch = cid & 31;
  int rbase = b * T + ch * CH;
  __shared__ float lc[CH], wts[CH];
  __shared__ float krs[CH][68], avs[CH][68];
  int tid = threadIdx.x;

  if (tid < 64) {
    float al = alw[rbase + tid], kn = knw[rbase + tid];
    float gate = al * kn * 0.1f;
    float sp = (gate > 20.f) ? gate : log1pf(expf(gate));
    float g = expf(-sp);
    float v = logf(g + 1e-8f);
#pragma unroll
    for (int off = 1; off < 64; off <<= 1) {
      float n = __shfl_up(v, off, 64);
      if (tid >= off) v += n;
    }
    lc[tid] = v;
    if (half == 0) lcum[rbase + tid] = v;
  }
  for (int i = tid; i < 512; i += 256) {
    int t = i >> 3, c8 = i & 7;
    uint4 kv = *(const uint4*)&krb[(size_t)(rbase + t) * S + c8 * 8];
    uint4 a4 = *(const uint4*)&avb[(size_t)(rbase + t) * S + c8 * 8];
    const ushort* kh = (const ushort*)&kv;
    const ushort* ah = (const ushort*)&a4;
    float kf[8], af_[8];
#pragma unroll
    for (int j = 0; j < 8; ++j) { kf[j] = b2f(kh[j]); af_[j] = b2f(ah[j]); }
    *(float4*)&krs[t][c8 * 8]     = *(const float4*)&kf[0];
    *(float4*)&krs[t][c8 * 8 + 4] = *(const float4*)&kf[4];
    *(float4*)&avs[t][c8 * 8]     = *(const float4*)&af_[0];
    *(float4*)&avs[t][c8 * 8 + 4] = *(const float4*)&af_[4];
  }
  __syncthreads();
  float tot = lc[63];
  if (tid < 64) wts[tid] = __expf(tot - lc[tid]);   // exponent <= 0
  if (tid == 63 && half == 0) csum[b * NC + ch] = tot;
  __syncthreads();
  for (int i = tid; i < 2048; i += 256) {           // this half's v-range transpose
    int v = half * 32 + (i >> 6), t = i & 63;
    avT[(size_t)(b * NC + ch) * 4096 + v * 64 + t] = f2b(avs[t][v]);
  }
  int k = tid & 63, vg = tid >> 6;
  int v0 = half * 32 + vg * 8;
  float acc[8];
#pragma unroll
  for (int j = 0; j < 8; ++j) acc[j] = 0.f;
  for (int t = 0; t < CH; ++t) {
    float kw = krs[t][k] * wts[t];
    float4 a0 = *(const float4*)&avs[t][v0];
    float4 a1 = *(const float4*)&avs[t][v0 + 4];
    acc[0] += kw * a0.x; acc[1] += kw * a0.y; acc[2] += kw * a0.z; acc[3] += kw * a0.w;
    acc[4] += kw * a1.x; acc[5] += kw * a1.y; acc[6] += kw * a1.z; acc[7] += kw * a1.w;
  }
  size_t ob = (size_t)(b * NC + ch) * 4096;
#pragma unroll
  for (int j = 0; j < 8; ++j) Mc[ob + (v0 + j) * 64 + k] = acc[j];
}

// ---------------- chunk-level scan: preloaded Mc; 256 blocks x 64 threads
__global__ __launch_bounds__(64) void k_scan(const float* __restrict__ state,
                                             const float* __restrict__ csum,
                                             const float* __restrict__ Mc,
                                             ushort* __restrict__ Scb,
                                             float* __restrict__ newstate) {
  int gid = blockIdx.x * 64 + threadIdx.x;   // B*S*S = 16384
  int b = gid >> 12, e = gid & 4095;
  __shared__ float eg[NC];
  if (threadIdx.x < NC) eg[threadIdx.x] = __expf(csum[b * NC + threadIdx.x]);
  float m[NC];
#pragma unroll
  for (int c = 0; c < NC; ++c) m[c] = Mc[(size_t)(b * NC + c) * 4096 + e];
  float s = state[gid];
  __syncthreads();
#pragma unroll
  for (int c = 0; c < NC; ++c) {
    Scb[(size_t)(b * NC + c) * 4096 + e] = f2b(s);
    s = s * eg[c] + m[c];
  }
  newstate[gid] = s;
}

// ---------------- fused intra-chunk attention + output GEMM, 512 threads (8 waves)
// waves 0-3: attn (3 small GEMMs) + ret->LDS; waves 4-7 hold prefetched Wout frags.
// out-GEMM: all 8 waves, 32 cols x 2 g-groups each (N=512 per block).
__global__ __launch_bounds__(512) void k_ao(const ushort* __restrict__ qrb,
                                            const ushort* __restrict__ krb,
                                            const ushort* __restrict__ avT,
                                            const ushort* __restrict__ Scb,
                                            const float* __restrict__ lcum,
                                            const ushort* __restrict__ Wo,
                                            const float* __restrict__ bout,
                                            float* __restrict__ out) {
  int bid = blockIdx.x;
  int cid = (bid >> 4) * 8 + (bid & 7), nh = (bid >> 3) & 1;
  int b = cid >> 5, ch = cid & 31;
  int rbase = b * T + ch * CH;
  size_t cb2 = (size_t)(b * NC + ch) * 4096;
  __shared__ ushort qs[64 * 64], ks_[64 * 64], vs[64 * 64], ss[64 * 64], ps[64 * 64];
  __shared__ float lcv[CH];
  int tid = threadIdx.x;
  int wv = tid >> 6, l = tid & 63, lr = l >> 4, lc = l & 15;
  int colw = nh * 512 + wv * 32;

  // early-issue g=0 Wout frags (latency hides under staging + attn)
  bf16x8 bw[2][4];
#pragma unroll
  for (int ni = 0; ni < 2; ++ni)
#pragma unroll
    for (int ks = 0; ks < 2; ++ks)
      bw[0][ni * 2 + ks] = *(const bf16x8*)&Wo[(size_t)(colw + ni * 16 + lc) * 64 + (ks * 4 + lr) * 8];

  if (tid < 64) lcv[tid] = lcum[rbase + tid];
  {
    int row = tid >> 3, c8 = tid & 7;      // 512 threads = 512 chunk-slots
    int sc = (c8 ^ (row & 7)) << 3;
    *(uint4*)&qs[row * 64 + c8 * 8]  = *(const uint4*)&qrb[(size_t)(rbase + row) * S + sc];
    *(uint4*)&ks_[row * 64 + c8 * 8] = *(const uint4*)&krb[(size_t)(rbase + row) * S + sc];
    *(uint4*)&vs[row * 64 + c8 * 8]  = *(const uint4*)&avT[cb2 + row * 64 + sc];
    *(uint4*)&ss[row * 64 + c8 * 8]  = *(const uint4*)&Scb[cb2 + row * 64 + sc];
  }
  __syncthreads();

  int tq = (wv & 3) * 16;
  f32x4 a2[4];
#pragma unroll
  for (int ni = 0; ni < 4; ++ni) a2[ni] = (f32x4){0, 0, 0, 0};

  if (wv < 4) {
    f32x4 a1[4];
#pragma unroll
    for (int ni = 0; ni < 4; ++ni) a1[ni] = (f32x4){0, 0, 0, 0};
    bf16x8 qa[2];
#pragma unroll
    for (int ks = 0; ks < 2; ++ks)
      qa[ks] = *(const bf16x8*)&qs[(tq + lc) * 64 + (((ks * 4 + lr) ^ (lc & 7)) << 3)];
#pragma unroll
    for (int ni = 0; ni < 4; ++ni)
#pragma unroll
      for (int ks = 0; ks < 2; ++ks) {
        bf16x8 kf = *(const bf16x8*)&ks_[(ni * 16 + lc) * 64 + (((ks * 4 + lr) ^ (lc & 7)) << 3)];
        bf16x8 sf = *(const bf16x8*)&ss[(ni * 16 + lc) * 64 + (((ks * 4 + lr) ^ (lc & 7)) << 3)];
        a1[ni] = __builtin_amdgcn_mfma_f32_16x16x32_bf16(qa[ks], kf, a1[ni], 0, 0, 0);
        a2[ni] = __builtin_amdgcn_mfma_f32_16x16x32_bf16(qa[ks], sf, a2[ni], 0, 0, 0);
      }
    // P = mask(dot)*exp(sh_t - lc_s) -> ps (swizzled); a2 *= exp(sh_t)
#pragma unroll
    for (int r = 0; r < 4; ++r) {
      int trow = tq + lr * 4 + r;
      float sh = trow ? lcv[trow - 1] : 0.f;
      float esh = __expf(sh);
#pragma unroll
      for (int ni = 0; ni < 4; ++ni) {
        int scol = ni * 16 + lc;
        float pv = (scol < trow) ? a1[ni][r] * __expf(sh - lcv[scol]) : 0.f;
        ps[trow * 64 + (((scol >> 3) ^ (trow & 7)) << 3) + (scol & 7)] = f2b(pv);
        a2[ni][r] *= esh;
      }
    }
  }
  __syncthreads();
  if (wv < 4) {
    // GEMM3: ret += P @ avT
    bf16x8 pa[2];
#pragma unroll
    for (int ks = 0; ks < 2; ++ks)
      pa[ks] = *(const bf16x8*)&ps[(tq + lc) * 64 + (((ks * 4 + lr) ^ (lc & 7)) << 3)];
#pragma unroll
    for (int ni = 0; ni < 4; ++ni)
#pragma unroll
      for (int ks = 0; ks < 2; ++ks) {
        bf16x8 vf = *(const bf16x8*)&vs[(ni * 16 + lc) * 64 + (((ks * 4 + lr) ^ (lc & 7)) << 3)];
        a2[ni] = __builtin_amdgcn_mfma_f32_16x16x32_bf16(pa[ks], vf, a2[ni], 0, 0, 0);
      }
    // write ret (bf16) into ks_ as the out-GEMM A tile (swizzled rows)
#pragma unroll
    for (int r = 0; r < 4; ++r) {
      int trow = tq + lr * 4 + r;
#pragma unroll
      for (int ni = 0; ni < 4; ++ni) {
        int scol = ni * 16 + lc;
        ks_[trow * 64 + (((scol >> 3) ^ (trow & 7)) << 3) + (scol & 7)] = f2b(a2[ni][r]);
      }
    }
  }
  __syncthreads();

  // ---------- out-GEMM: M=64 x N=512 (this half) x K=64, 8 waves
  // prefetch g=1 frags first (long latency), then LDS A-frags
#pragma unroll
  for (int ni = 0; ni < 2; ++ni)
#pragma unroll
    for (int ks = 0; ks < 2; ++ks)
      bw[1][ni * 2 + ks] = *(const bf16x8*)&Wo[(size_t)(colw + 256 + ni * 16 + lc) * 64 + (ks * 4 + lr) * 8];
  bf16x8 afr[4][2];
#pragma unroll
  for (int mi = 0; mi < 4; ++mi)
#pragma unroll
    for (int ks = 0; ks < 2; ++ks)
      afr[mi][ks] = *(const bf16x8*)&ks_[(mi * 16 + lc) * 64 + (((ks * 4 + lr) ^ (lc & 7)) << 3)];

#pragma unroll
  for (int g = 0; g < 2; ++g) {
    f32x4 acc[4][2];
#pragma unroll
    for (int mi = 0; mi < 4; ++mi)
#pragma unroll
      for (int ni = 0; ni < 2; ++ni) acc[mi][ni] = (f32x4){0.f, 0.f, 0.f, 0.f};
#pragma unroll
    for (int ks = 0; ks < 2; ++ks)
#pragma unroll
      for (int mi = 0; mi < 4; ++mi)
#pragma unroll
        for (int ni = 0; ni < 2; ++ni)
          acc[mi][ni] = __builtin_amdgcn_mfma_f32_16x16x32_bf16(afr[mi][ks], bw[g][ni * 2 + ks], acc[mi][ni], 0, 0, 0);
    float bo[2];
#pragma unroll
    for (int ni = 0; ni < 2; ++ni) bo[ni] = bout[colw + g * 256 + ni * 16 + lc];
#pragma unroll
    for (int mi = 0; mi < 4; ++mi)
#pragma unroll
      for (int r = 0; r < 4; ++r) {
        int grow = rbase + mi * 16 + lr * 4 + r;
#pragma unroll
        for (int ni = 0; ni < 2; ++ni)
          out[(size_t)grow * D + colw + g * 256 + ni * 16 + lc] = acc[mi][ni][r] + bo[ni];
      }
  }
}

extern "C" void kernel_launch(void* const* d_in, const int* in_sizes, int n_in,
                              void* d_out, int out_size, void* d_ws, size_t ws_size,
                              hipStream_t stream) {
  (void)in_sizes; (void)n_in; (void)out_size; (void)ws_size;
  const float* x     = (const float*)d_in[0];
  const float* state = (const float*)d_in[1];
  const float* Wk    = (const float*)d_in[2];
  const float* Wv    = (const float*)d_in[3];
  const float* Wq    = (const float*)d_in[4];
  const float* Wout  = (const float*)d_in[5];
  const float* bout  = (const float*)d_in[6];
  const float* Wg    = (const float*)d_in[7];
  const float* bg    = (const float*)d_in[8];
  const float* cosT  = (const float*)d_in[9];
  const float* sinT  = (const float*)d_in[10];

  float* out = (float*)d_out;
  float* newstate = out + (size_t)B * T * D;

  const int NTOK = B * T;            // 8192
  const int NE = B * T * S;          // 524288
  ushort* Wt   = (ushort*)d_ws;      // 262144
  ushort* Wo   = Wt + 262144;        // 65536
  ushort* qrb  = Wo + 65536;
  ushort* krb  = qrb + NE;
  ushort* avb  = krb + NE;
  ushort* avT  = avb + NE;
  ushort* Scb  = avT + NE;           // B*NC*4096 = NE
  float* knw   = (float*)(Scb + NE);
  float* alw   = knw + NTOK;
  float* lcum  = alw + NTOK;
  float* csum  = lcum + NTOK;        // B*NC
  float* Mc    = csum + B * NC;      // NE floats

  hipLaunchKernelGGL(k_prep, dim3(1280), dim3(256), 0, stream, Wk, Wv, Wq, Wg, Wout, Wt, Wo);
  hipLaunchKernelGGL(k_proj, dim3(NTOK / 32 * 2), dim3(256), 0, stream, x, Wt, cosT, sinT, bg, qrb, krb, avb, knw, alw);
  hipLaunchKernelGGL(k_chunk, dim3(B * NC * 2), dim3(256), 0, stream, krb, avb, knw, alw, lcum, csum, Mc, avT);
  hipLaunchKernelGGL(k_scan, dim3(B * S * S / 64), dim3(64), 0, stream, state, csum, Mc, Scb, newstate);
  hipLaunchKernelGGL(k_ao, dim3(B * NC * 2), dim3(512), 0, stream, qrb, krb, avT, Scb, lcum, Wo, bout, out);
}